// Round 3
// baseline (1130.567 us; speedup 1.0000x reference)
//
#include <hip/hip_runtime.h>
#include <cstddef>

// ============================================================================
// AlexCapsNet CIFAR-100 forward. Round 9: backbone convs rewritten around
// pre-split bf16 activations. All conv tensors live as NHWC bf16 hi/lo ushort
// planes; weights pre-transposed to [co][(dh,dw)][ci] hi/lo planes once.
// convgemm hot loop has ZERO fp32->bf16 cvt work: A (im2col pixels) and B
// (weights) load packed uint4 directly; LDS staged linearly ([t]) -> no bank
// conflicts. Routing + FC head unchanged from round 8.
// ============================================================================

typedef __attribute__((ext_vector_type(8))) short bf8_t;   // 8 bf16 (4 VGPR)
typedef __attribute__((ext_vector_type(4))) float f4_t;    // 4 fp32 acc

// pack 8 fp32 -> 4 dwords of bf16-hi pairs + 4 dwords of bf16-lo pairs
__device__ inline void cvt_hilo8(const float* f, unsigned* h, unsigned* l)
{
  #pragma unroll
  for (int j = 0; j < 4; ++j) {
    unsigned u0 = __float_as_uint(f[2 * j]);
    unsigned u1 = __float_as_uint(f[2 * j + 1]);
    h[j] = (u0 >> 16) | (u1 & 0xFFFF0000u);
    float r0 = f[2 * j]     - __uint_as_float(u0 & 0xFFFF0000u);
    float r1 = f[2 * j + 1] - __uint_as_float(u1 & 0xFFFF0000u);
    l[j] = (__float_as_uint(r0) >> 16) | (__float_as_uint(r1) & 0xFFFF0000u);
  }
}

// truncating hi/lo split of one fp32 (same math as cvt_hilo8)
__device__ inline void split1(float f, unsigned short& h, unsigned short& l)
{
  unsigned u = __float_as_uint(f);
  h = (unsigned short)(u >> 16);
  float r = f - __uint_as_float(u & 0xFFFF0000u);
  l = (unsigned short)(__float_as_uint(r) >> 16);
}

__device__ inline float bf2f(unsigned short h, unsigned short l)
{
  return __uint_as_float((unsigned)h << 16) + __uint_as_float((unsigned)l << 16);
}

// ---------- weight transpose+split: w[co][ci][r9] f32 -> [co][r9][ci] bf16 hi/lo
__global__ __launch_bounds__(256) void wsplit_k(
    const float* __restrict__ w, unsigned short* __restrict__ oh,
    unsigned short* __restrict__ ol, int CO, int CI)
{
  int idx = blockIdx.x * 256 + threadIdx.x;          // grid sized exactly
  int ci = idx % CI;
  int t2 = idx / CI;
  int r = t2 % 9, co = t2 / 9;
  float f = w[((size_t)co * CI + ci) * 9 + r];
  unsigned short h, l;
  split1(f, h, l);
  oh[idx] = h; ol[idx] = l;
}

// ---------- conv1: 3->96 k3 s1 p1 + relu -> NHWC bf16 hi/lo ----------
__global__ __launch_bounds__(256) void conv1_k(
    const float* __restrict__ x, const float* __restrict__ wt,
    const float* __restrict__ bias, unsigned short* __restrict__ oh,
    unsigned short* __restrict__ ol)
{
  int idx = blockIdx.x * 256 + threadIdx.x;     // (b, h, w)
  int w = idx & 31, h = (idx >> 5) & 31, b = idx >> 10;
  int co0 = blockIdx.y * 24;                    // co-slice

  float xv[27];
  const float* xb = x + (size_t)b * 3072;
  #pragma unroll
  for (int ci = 0; ci < 3; ++ci)
    #pragma unroll
    for (int dh = 0; dh < 3; ++dh) {
      int ih = h + dh - 1;
      #pragma unroll
      for (int dw = 0; dw < 3; ++dw) {
        int iw = w + dw - 1;
        bool ok = ((unsigned)ih < 32u) & ((unsigned)iw < 32u);
        xv[ci * 9 + dh * 3 + dw] = ok ? xb[(ci << 10) + (ih << 5) + iw] : 0.f;
      }
    }

  size_t obase = ((size_t)b * 1024 + (h << 5) + w) * 96 + co0;
  const float* wp = wt + (size_t)co0 * 27;      // wave-uniform -> s_load
  #pragma unroll 2
  for (int cp = 0; cp < 12; ++cp) {
    float a0 = bias[co0 + 2 * cp], a1 = bias[co0 + 2 * cp + 1];
    #pragma unroll
    for (int k = 0; k < 27; ++k) {
      a0 += xv[k] * wp[(2 * cp) * 27 + k];
      a1 += xv[k] * wp[(2 * cp + 1) * 27 + k];
    }
    a0 = fmaxf(a0, 0.f); a1 = fmaxf(a1, 0.f);
    unsigned short h0, l0, h1, l1;
    split1(a0, h0, l0); split1(a1, h1, l1);
    *(unsigned*)(oh + obase + 2 * cp) = (unsigned)h0 | ((unsigned)h1 << 16);
    *(unsigned*)(ol + obase + 2 * cp) = (unsigned)l0 | ((unsigned)l1 << 16);
  }
}

// ---------- maxpool k3 s2 p1 on NHWC bf16 hi/lo pairs ----------
template <int C, int H>
__global__ __launch_bounds__(256) void maxpool_bf(
    const unsigned short* __restrict__ inh, const unsigned short* __restrict__ inl,
    unsigned short* __restrict__ outh, unsigned short* __restrict__ outl)
{
  constexpr int Ho = H >> 1;
  int idx = blockIdx.x * 256 + threadIdx.x;
  int c = idx % C;
  int q = idx / C;
  int wo = q % Ho;
  int q2 = q / Ho;
  int ho = q2 % Ho, b = q2 / Ho;
  float best = -3.4e38f;
  unsigned short bh = 0, bl = 0;
  #pragma unroll
  for (int dh = 0; dh < 3; ++dh) {
    int ih = 2 * ho - 1 + dh;
    if ((unsigned)ih >= (unsigned)H) continue;
    #pragma unroll
    for (int dw = 0; dw < 3; ++dw) {
      int iw = 2 * wo - 1 + dw;
      if ((unsigned)iw >= (unsigned)H) continue;
      size_t off = ((size_t)(b * H + ih) * H + iw) * C + c;
      unsigned short uh = inh[off], ul = inl[off];
      float f = bf2f(uh, ul);
      if (f > best) { best = f; bh = uh; bl = ul; }
    }
  }
  outh[idx] = bh; outl[idx] = bl;
}

// ---------- conv as MFMA GEMM, NHWC bf16 hi/lo in, im2col on the fly ----------
// A = activations (M = b*WO*WO pixels), B = weights (N = CO).
// K order = (dh,dw,ci); weights pre-transposed to [co][r][ci] hi/lo.
// LDS staged [kgroup=wave][row=lane] -> all LDS writes linear ([t]).
template <int CI, int H, int PAD, int WO, bool SPLIT>
__global__ __launch_bounds__(256) void convgemm_nhwc(
    const unsigned short* __restrict__ inh, const unsigned short* __restrict__ inl,
    const unsigned short* __restrict__ wh, const unsigned short* __restrict__ wl,
    const float* __restrict__ bias, unsigned short* __restrict__ outh,
    unsigned short* __restrict__ outl, float* __restrict__ outf,
    int CO, int relu, int KC)
{
  constexpr int K = CI * 9;
  constexpr int NPIX = WO * WO;
  __shared__ uint4 Ah[256], Al[256], Bh[256], Bl[256];
  int n0 = blockIdx.x * 64, m0 = blockIdx.y * 64;
  int kbeg = SPLIT ? blockIdx.z * KC : 0;
  int kend = SPLIT ? kbeg + KC : K;
  int t = threadIdx.x;
  int lane = t & 63;
  int wave = __builtin_amdgcn_readfirstlane(t >> 6);
  int wm = wave & 1, wn = wave >> 1;
  int lr = lane & 15, lq = lane >> 4;

  // A-side pixel for this thread (fixed across k loop)
  int nn = m0 + lane;
  int bpix = nn / NPIX, xy = nn - bpix * NPIX;
  int ho = xy / WO, wo = xy - ho * WO;
  int ih0 = ho - PAD, iw0 = wo - PAD;
  size_t ibase = (size_t)bpix * H * H;

  uint4 a_h, a_l, b_h, b_l;
  auto loadA = [&](int k0) {
    int kk = k0 + wave * 8;
    int r = kk / CI, ci0 = kk - r * CI;
    int dh = r / 3, dw = r - dh * 3;
    int ih = ih0 + dh, iw = iw0 + dw;
    bool ok = ((unsigned)ih < (unsigned)H) & ((unsigned)iw < (unsigned)H);
    if (ok) {
      size_t ad = ((ibase + (size_t)ih * H + iw) * CI + ci0);
      a_h = *(const uint4*)(inh + ad);
      a_l = *(const uint4*)(inl + ad);
    } else {
      a_h = make_uint4(0u, 0u, 0u, 0u);
      a_l = make_uint4(0u, 0u, 0u, 0u);
    }
  };
  auto loadB = [&](int k0) {
    int kk = k0 + wave * 8;
    size_t ad = (size_t)(n0 + lane) * K + kk;
    b_h = *(const uint4*)(wh + ad);
    b_l = *(const uint4*)(wl + ad);
  };

  loadA(kbeg); loadB(kbeg);
  f4_t acc[2][2];
  #pragma unroll
  for (int mt = 0; mt < 2; ++mt)
    #pragma unroll
    for (int nt = 0; nt < 2; ++nt) acc[mt][nt] = (f4_t)0.0f;

  for (int k0 = kbeg; k0 < kend; k0 += 32) {
    if (k0 > kbeg) __syncthreads();
    Ah[t] = a_h; Al[t] = a_l; Bh[t] = b_h; Bl[t] = b_l;
    __syncthreads();
    if (k0 + 32 < kend) { loadA(k0 + 32); loadB(k0 + 32); }
    bf8_t av_h[2], av_l[2], bv_h[2], bv_l[2];
    #pragma unroll
    for (int mt = 0; mt < 2; ++mt) {
      int ui = lq * 64 + wm * 32 + mt * 16 + lr;
      av_h[mt] = *(const bf8_t*)&Ah[ui];
      av_l[mt] = *(const bf8_t*)&Al[ui];
    }
    #pragma unroll
    for (int nt = 0; nt < 2; ++nt) {
      int ui = lq * 64 + wn * 32 + nt * 16 + lr;
      bv_h[nt] = *(const bf8_t*)&Bh[ui];
      bv_l[nt] = *(const bf8_t*)&Bl[ui];
    }
    #pragma unroll
    for (int mt = 0; mt < 2; ++mt)
      #pragma unroll
      for (int nt = 0; nt < 2; ++nt) {
        acc[mt][nt] = __builtin_amdgcn_mfma_f32_16x16x32_bf16(av_h[mt], bv_h[nt], acc[mt][nt], 0, 0, 0);
        acc[mt][nt] = __builtin_amdgcn_mfma_f32_16x16x32_bf16(av_h[mt], bv_l[nt], acc[mt][nt], 0, 0, 0);
        acc[mt][nt] = __builtin_amdgcn_mfma_f32_16x16x32_bf16(av_l[mt], bv_h[nt], acc[mt][nt], 0, 0, 0);
      }
  }
  // D: row = pixel m, col = co n. NHWC flat = m*CO + n (div-free).
  #pragma unroll
  for (int mt = 0; mt < 2; ++mt)
    #pragma unroll
    for (int nt = 0; nt < 2; ++nt) {
      #pragma unroll
      for (int r = 0; r < 4; ++r) {
        int m = m0 + wm * 32 + mt * 16 + lq * 4 + r;
        int n = n0 + wn * 32 + nt * 16 + lr;
        size_t oidx = (size_t)m * CO + n;
        if (SPLIT) {
          atomicAdd(outf + oidx, acc[mt][nt][r]);
        } else {
          float vv = acc[mt][nt][r] + bias[n];
          if (relu) vv = fmaxf(vv, 0.f);
          unsigned short h, l;
          split1(vv, h, l);
          outh[oidx] = h; outl[oidx] = l;
        }
      }
    }
}

// ---------- FC as bf16x2-split MFMA GEMM, split-K, atomic partials ----------
__global__ __launch_bounds__(256) void fc_mfma(
    const float* __restrict__ A, const float* __restrict__ W,
    float* __restrict__ C, int K, int N, int KC)
{
  __shared__ uint4 Ah[256], Al[256], Bh[256], Bl[256];
  int n0 = blockIdx.x * 64, m0 = blockIdx.y * 64;
  int kbeg = blockIdx.z * KC, kend = kbeg + KC;
  int t = threadIdx.x;
  int lane = t & 63;
  int wave = __builtin_amdgcn_readfirstlane(t >> 6);
  int wm = wave & 1, wn = wave >> 1;
  int lr = lane & 15, lq = lane >> 4;
  int smA = t >> 2, sgA = t & 3;

  float fa[8], fb[8];
  auto loadA = [&](int k0) {
    const float4* ap = (const float4*)(A + (size_t)(m0 + smA) * K + k0 + sgA * 8);
    float4 a0 = ap[0], a1 = ap[1];
    fa[0] = a0.x; fa[1] = a0.y; fa[2] = a0.z; fa[3] = a0.w;
    fa[4] = a1.x; fa[5] = a1.y; fa[6] = a1.z; fa[7] = a1.w;
  };
  auto loadB = [&](int k0) {
    const float* wp = W + (size_t)(k0 + wave * 8) * N + n0 + lane;
    #pragma unroll
    for (int j = 0; j < 8; ++j) fb[j] = wp[(size_t)j * N];
  };

  loadA(kbeg); loadB(kbeg);
  f4_t acc[2][2];
  #pragma unroll
  for (int mt = 0; mt < 2; ++mt)
    #pragma unroll
    for (int nt = 0; nt < 2; ++nt) acc[mt][nt] = (f4_t)0.0f;

  for (int k0 = kbeg; k0 < kend; k0 += 32) {
    if (k0 > kbeg) __syncthreads();
    unsigned ha[4], la[4], hb[4], lb[4];
    cvt_hilo8(fa, ha, la);
    cvt_hilo8(fb, hb, lb);
    Ah[sgA * 64 + smA] = make_uint4(ha[0], ha[1], ha[2], ha[3]);
    Al[sgA * 64 + smA] = make_uint4(la[0], la[1], la[2], la[3]);
    Bh[wave * 64 + lane] = make_uint4(hb[0], hb[1], hb[2], hb[3]);
    Bl[wave * 64 + lane] = make_uint4(lb[0], lb[1], lb[2], lb[3]);
    __syncthreads();
    if (k0 + 32 < kend) { loadA(k0 + 32); loadB(k0 + 32); }
    bf8_t av_h[2], av_l[2], bv_h[2], bv_l[2];
    #pragma unroll
    for (int mt = 0; mt < 2; ++mt) {
      int ui = lq * 64 + wm * 32 + mt * 16 + lr;
      av_h[mt] = *(const bf8_t*)&Ah[ui];
      av_l[mt] = *(const bf8_t*)&Al[ui];
    }
    #pragma unroll
    for (int nt = 0; nt < 2; ++nt) {
      int ui = lq * 64 + wn * 32 + nt * 16 + lr;
      bv_h[nt] = *(const bf8_t*)&Bh[ui];
      bv_l[nt] = *(const bf8_t*)&Bl[ui];
    }
    #pragma unroll
    for (int mt = 0; mt < 2; ++mt)
      #pragma unroll
      for (int nt = 0; nt < 2; ++nt) {
        acc[mt][nt] = __builtin_amdgcn_mfma_f32_16x16x32_bf16(av_h[mt], bv_h[nt], acc[mt][nt], 0, 0, 0);
        acc[mt][nt] = __builtin_amdgcn_mfma_f32_16x16x32_bf16(av_h[mt], bv_l[nt], acc[mt][nt], 0, 0, 0);
        acc[mt][nt] = __builtin_amdgcn_mfma_f32_16x16x32_bf16(av_l[mt], bv_h[nt], acc[mt][nt], 0, 0, 0);
      }
  }
  #pragma unroll
  for (int mt = 0; mt < 2; ++mt)
    #pragma unroll
    for (int nt = 0; nt < 2; ++nt) {
      #pragma unroll
      for (int r = 0; r < 4; ++r) {
        int m = m0 + wm * 32 + mt * 16 + lq * 4 + r;
        int n = n0 + wn * 32 + nt * 16 + lr;
        atomicAdd(C + (size_t)m * N + n, acc[mt][nt][r]);
      }
    }
}

// ---------- squash8 + pcaps bias; p[b,pix36,co256] NHWC -> u_t[i,e,b] ----------
__global__ __launch_bounds__(256) void squash8_k(
    const float* __restrict__ p, const float* __restrict__ pb,
    float* __restrict__ ut)
{
  int idx = blockIdx.x * 256 + threadIdx.x;
  if (idx >= 147456) return;
  int b = idx & 127, i = idx >> 7;
  float pv[8];
  #pragma unroll
  for (int e = 0; e < 8; ++e) {
    int f = i * 8 + e;
    int co = f / 36, pix = f - co * 36;
    pv[e] = p[((size_t)b * 36 + pix) * 256 + co] + pb[co];
  }
  float n2 = 0.f;
  #pragma unroll
  for (int e = 0; e < 8; ++e) n2 += pv[e] * pv[e];
  float sc = (n2 / (1.f + n2)) * rsqrtf(n2 + 1e-8f);
  #pragma unroll
  for (int e = 0; e < 8; ++e)
    ut[(size_t)i * 1024 + e * 128 + b] = pv[e] * sc;
}

// ---------- squash16: s[b,o,16] -> v[b,o,16] + v_t[o,d,b] ----------
__global__ __launch_bounds__(256) void caps_squash16(
    const float* __restrict__ s, float* __restrict__ v, float* __restrict__ vt)
{
  int idx = blockIdx.x * 256 + threadIdx.x;
  if (idx >= 12800) return;
  int b = idx / 100, o = idx % 100;
  const float4* sp = (const float4*)(s + (size_t)idx * 16);
  float4 a = sp[0], bb = sp[1], c = sp[2], d = sp[3];
  float n2 = a.x * a.x + a.y * a.y + a.z * a.z + a.w * a.w +
             bb.x * bb.x + bb.y * bb.y + bb.z * bb.z + bb.w * bb.w +
             c.x * c.x + c.y * c.y + c.z * c.z + c.w * c.w +
             d.x * d.x + d.y * d.y + d.z * d.z + d.w * d.w;
  float sc = (n2 / (1.f + n2)) * rsqrtf(n2 + 1e-8f);
  float vv[16] = {a.x, a.y, a.z, a.w, bb.x, bb.y, bb.z, bb.w,
                  c.x, c.y, c.z, c.w, d.x, d.y, d.z, d.w};
  float4* vp = (float4*)(v + (size_t)idx * 16);
  float4 o0 = {vv[0] * sc, vv[1] * sc, vv[2] * sc, vv[3] * sc};
  float4 o1 = {vv[4] * sc, vv[5] * sc, vv[6] * sc, vv[7] * sc};
  float4 o2 = {vv[8] * sc, vv[9] * sc, vv[10] * sc, vv[11] * sc};
  float4 o3 = {vv[12] * sc, vv[13] * sc, vv[14] * sc, vv[15] * sc};
  vp[0] = o0; vp[1] = o1; vp[2] = o2; vp[3] = o3;
  #pragma unroll
  for (int dd = 0; dd < 16; ++dd)
    vt[((size_t)o * 16 + dd) * 128 + b] = vv[dd] * sc;
}

// ---------- routing s-pass as per-o MFMA GEMM ----------
__global__ __launch_bounds__(256) void caps_spass_mfma(
    const float* __restrict__ W, const float* __restrict__ ut,
    const float* __restrict__ ct, float* __restrict__ s, int uniform)
{
  __shared__ uint4 Ah[512], Al[512];               // [quad(4)][b(128)] 8KB each
  int o = blockIdx.x, ks = blockIdx.y;
  int t = threadIdx.x;
  int lane = t & 63;
  int wave = __builtin_amdgcn_readfirstlane(t >> 6);
  int lr = lane & 15, lq = lane >> 4;
  int b = t & 127, half = t >> 7;                  // staging role
  int i0 = ks * 144;

  float fu[16], fc[2], fw[8];
  auto loadUC = [&](int j) {
    int ib = i0 + j * 4 + half * 2;
    #pragma unroll
    for (int q = 0; q < 2; ++q) {
      int i = ib + q;
      #pragma unroll
      for (int e = 0; e < 8; ++e)
        fu[q * 8 + e] = ut[(size_t)i * 1024 + e * 128 + b];   // coalesced
      fc[q] = uniform ? 0.01f : ct[((size_t)o * 1152 + i) * 128 + b];
    }
  };
  auto loadW = [&](int j) {
    int i = i0 + j * 4 + lq;
    const float4* wp = (const float4*)(W + (((size_t)o * 1152 + i) * 16 + lr) * 8);
    float4 w0 = wp[0], w1 = wp[1];
    fw[0] = w0.x; fw[1] = w0.y; fw[2] = w0.z; fw[3] = w0.w;
    fw[4] = w1.x; fw[5] = w1.y; fw[6] = w1.z; fw[7] = w1.w;
  };

  loadUC(0); loadW(0);
  f4_t acc[2];
  acc[0] = (f4_t)0.0f; acc[1] = (f4_t)0.0f;

  for (int j = 0; j < 36; ++j) {
    float cu[16];
    #pragma unroll
    for (int q = 0; q < 2; ++q)
      #pragma unroll
      for (int e = 0; e < 8; ++e)
        cu[q * 8 + e] = fc[q] * fu[q * 8 + e];
    unsigned h0[4], l0[4], h1[4], l1[4], wh[4], wl[4];
    cvt_hilo8(cu, h0, l0);
    cvt_hilo8(cu + 8, h1, l1);
    cvt_hilo8(fw, wh, wl);                          // current W split (before prefetch)
    uint4 uwh = make_uint4(wh[0], wh[1], wh[2], wh[3]);
    uint4 uwl = make_uint4(wl[0], wl[1], wl[2], wl[3]);
    bf8_t bfh = *(const bf8_t*)&uwh;
    bf8_t bfl = *(const bf8_t*)&uwl;
    if (j > 0) __syncthreads();
    Ah[(half * 2 + 0) * 128 + b] = make_uint4(h0[0], h0[1], h0[2], h0[3]);
    Al[(half * 2 + 0) * 128 + b] = make_uint4(l0[0], l0[1], l0[2], l0[3]);
    Ah[(half * 2 + 1) * 128 + b] = make_uint4(h1[0], h1[1], h1[2], h1[3]);
    Al[(half * 2 + 1) * 128 + b] = make_uint4(l1[0], l1[1], l1[2], l1[3]);
    __syncthreads();
    if (j + 1 < 36) { loadUC(j + 1); loadW(j + 1); }
    #pragma unroll
    for (int mt = 0; mt < 2; ++mt) {
      int bidx = wave * 16 + mt * 64 + lr;
      bf8_t avh = *(const bf8_t*)&Ah[lq * 128 + bidx];
      bf8_t avl = *(const bf8_t*)&Al[lq * 128 + bidx];
      acc[mt] = __builtin_amdgcn_mfma_f32_16x16x32_bf16(avh, bfh, acc[mt], 0, 0, 0);
      acc[mt] = __builtin_amdgcn_mfma_f32_16x16x32_bf16(avh, bfl, acc[mt], 0, 0, 0);
      acc[mt] = __builtin_amdgcn_mfma_f32_16x16x32_bf16(avl, bfh, acc[mt], 0, 0, 0);
    }
  }
  // D layout: col(d)=lane&15, row(b)=lq*4+r
  #pragma unroll
  for (int mt = 0; mt < 2; ++mt)
    #pragma unroll
    for (int r = 0; r < 4; ++r) {
      int bb = wave * 16 + mt * 64 + lq * 4 + r;
      atomicAdd(s + ((size_t)bb * 100 + o) * 16 + lr, acc[mt][r]);
    }
}

// ---------- routing b-update as MFMA ----------
__global__ __launch_bounds__(256) void caps_bupdate(
    const float* __restrict__ W, const float* __restrict__ ut,
    const float* __restrict__ vt, float* __restrict__ blogt, int accum)
{
  __shared__ __align__(16) float Wt[64 * 160];   // [li][e(stride 20)][d] 40KB
  int o = blockIdx.x, ic = blockIdx.y;
  int t = threadIdx.x;
  int lane = t & 63;
  int wave = __builtin_amdgcn_readfirstlane(t >> 6);
  int lr = lane & 15, lq = lane >> 4;
  int dhalf = (lq & 1) << 3;        // which 8 d's this lq-quarter covers
  int hl = lq >> 1;                 // 0: hi plane (k<16), 1: lo plane (k>=16)

  {
    const float4* Wg = (const float4*)(W + ((size_t)o * 1152 + (size_t)ic * 64) * 128);
    for (int l = t; l < 2048; l += 256) {
      float4 w = Wg[l];
      int li = l >> 5;
      int rem = l & 31;
      int d = rem >> 1;
      int e0 = (rem & 1) << 2;
      float* dst = &Wt[li * 160 + e0 * 20 + d];
      dst[0] = w.x; dst[20] = w.y; dst[40] = w.z; dst[60] = w.w;
    }
  }

  bf8_t B1[8], B2[8];
  #pragma unroll
  for (int nt = 0; nt < 8; ++nt) {
    int b = nt * 16 + lr;
    float vv[8];
    #pragma unroll
    for (int j = 0; j < 8; ++j)
      vv[j] = vt[((size_t)o * 16 + dhalf + j) * 128 + b];
    unsigned h[4], l2[4];
    cvt_hilo8(vv, h, l2);
    uint4 uh = make_uint4(h[0], h[1], h[2], h[3]);
    uint4 ul = (lq < 2) ? make_uint4(l2[0], l2[1], l2[2], l2[3])
                        : make_uint4(0u, 0u, 0u, 0u);
    B1[nt] = *(const bf8_t*)&uh;
    B2[nt] = *(const bf8_t*)&ul;
  }
  __syncthreads();

  unsigned lomask = hl ? 0xFFFF0000u : 0u;

  for (int mi = 0; mi < 8; ++mi) {
    int mt = wave * 8 + mi;
    int liA = mt * 2 + (lr >> 3);
    int eA = lr & 7;
    const float* wp = &Wt[liA * 160 + eA * 20 + dhalf];
    float4 wa = *(const float4*)wp;
    float4 wb = *(const float4*)(wp + 4);
    float fw[8] = {wa.x, wa.y, wa.z, wa.w, wb.x, wb.y, wb.z, wb.w};
    unsigned ha[4];
    #pragma unroll
    for (int j = 0; j < 4; ++j) {
      float f0 = fw[2 * j], f1 = fw[2 * j + 1];
      f0 -= __uint_as_float(__float_as_uint(f0) & lomask);
      f1 -= __uint_as_float(__float_as_uint(f1) & lomask);
      ha[j] = (__float_as_uint(f0) >> 16) | (__float_as_uint(f1) & 0xFFFF0000u);
    }
    uint4 ua = make_uint4(ha[0], ha[1], ha[2], ha[3]);
    bf8_t A = *(const bf8_t*)&ua;

    int gi = ic * 64 + mt * 2 + hl;
    const float* up = ut + (size_t)gi * 1024 + (size_t)(((lq & 1) << 2)) * 128;
    #pragma unroll
    for (int nt = 0; nt < 8; ++nt) {
      f4_t acc = (f4_t)0.0f;
      acc = __builtin_amdgcn_mfma_f32_16x16x32_bf16(A, B1[nt], acc, 0, 0, 0);
      acc = __builtin_amdgcn_mfma_f32_16x16x32_bf16(A, B2[nt], acc, 0, 0, 0);
      int b = nt * 16 + lr;
      float p = acc[0] * up[b] + acc[1] * up[128 + b] +
                acc[2] * up[256 + b] + acc[3] * up[384 + b];
      p += __shfl_xor(p, 16);
      if (!(lq & 1)) {
        size_t off = ((size_t)o * 1152 + gi) * 128 + b;
        if (accum) blogt[off] += p; else blogt[off] = p;
      }
    }
  }
}

// ---------- softmax over o per (i,b), transposed layouts ----------
__global__ __launch_bounds__(256) void caps_softmax(
    const float* __restrict__ blogt, float* __restrict__ ct)
{
  int idx = blockIdx.x * 256 + threadIdx.x;
  if (idx >= 147456) return;
  const float* bp = blogt + idx;
  float m = -3.4e38f;
  for (int o = 0; o < 100; ++o) m = fmaxf(m, bp[(size_t)o * 147456]);
  float sum = 0.f;
  for (int o = 0; o < 100; ++o) sum += __expf(bp[(size_t)o * 147456] - m);
  float inv = 1.f / sum;
  for (int o = 0; o < 100; ++o)
    ct[(size_t)o * 147456 + idx] = __expf(bp[(size_t)o * 147456] - m) * inv;
}

// ---------- bias + optional relu, in place ----------
__global__ __launch_bounds__(256) void bias_act_k(
    float* __restrict__ C, const float* __restrict__ bias, int N, int total, int relu)
{
  int idx = blockIdx.x * 256 + threadIdx.x;
  if (idx >= total) return;
  float vv = C[idx] + bias[idx % N];
  if (relu) vv = fmaxf(vv, 0.f);
  C[idx] = vv;
}

// ---------- fc3 ----------
__global__ __launch_bounds__(128) void fc3_seed(
    const float* __restrict__ bias, float* __restrict__ out)
{
  int idx = blockIdx.x * 128 + threadIdx.x;
  if (idx < 12800) out[idx] = bias[idx % 100];
}

__global__ __launch_bounds__(128) void fc3_sk(
    const float* __restrict__ A, const float* __restrict__ W,
    float* __restrict__ out)
{
  __shared__ float Al[1024];
  int m = blockIdx.x, z = blockIdx.y, t = threadIdx.x;
  int kbeg = z * 1024;
  const float* ap = A + (size_t)m * 4096 + kbeg;
  for (int l = t; l < 1024; l += 128) Al[l] = ap[l];
  __syncthreads();
  if (t < 100) {
    float acc = 0.f;
    const float* wp = W + (size_t)kbeg * 100 + t;
    #pragma unroll 8
    for (int k = 0; k < 1024; ++k) acc += Al[k] * wp[(size_t)k * 100];
    atomicAdd(out + m * 100 + t, acc);
  }
}

// ============================================================================
extern "C" void kernel_launch(void* const* d_in, const int* in_sizes, int n_in,
                              void* d_out, int out_size, void* d_ws, size_t ws_size,
                              hipStream_t stream)
{
  (void)in_sizes; (void)n_in; (void)out_size; (void)ws_size;
  const float* x   = (const float*)d_in[0];
  const float* cw1 = (const float*)d_in[1];
  const float* cb1 = (const float*)d_in[2];
  const float* cw2 = (const float*)d_in[3];
  const float* cb2 = (const float*)d_in[4];
  const float* cw3 = (const float*)d_in[5];
  const float* cb3 = (const float*)d_in[6];
  const float* pw  = (const float*)d_in[7];
  const float* pb  = (const float*)d_in[8];
  const float* Wc  = (const float*)d_in[9];
  const float* fw1 = (const float*)d_in[10];
  const float* fb1 = (const float*)d_in[11];
  const float* fw2 = (const float*)d_in[12];
  const float* fb2 = (const float*)d_in[13];
  const float* fw3 = (const float*)d_in[14];
  const float* fb3 = (const float*)d_in[15];
  float* ws = (float*)d_ws;

  const size_t OFF_A  = 0;          // act planes; later blog_t [o,i,b]
  const size_t OFF_B  = 12582912;   // pooled planes
  const size_t OFF_U  = 15728640;   // u_t [1152,8,128]
  const size_t OFF_P  = 16908288;   // p [128,36,256] NHWC; later v_t [100,16,128]
  const size_t OFF_C  = 18087936;   // weight planes (backbone) / c_t (routing)
  const size_t OFF_V  = 32833536;   // v [128,100,16]
  const size_t OFF_S  = 33038336;   // s [128,100,16]
  const size_t OFF_F1 = 33243136;   // f1 [128,4096]
  const size_t OFF_F2 = 33767424;   // f2 [128,4096]

  float* ut    = ws + OFF_U;
  float* p     = ws + OFF_P;
  float* vt    = ws + OFF_P;        // reuses p region after squash8
  float* ct    = ws + OFF_C;
  float* v     = ws + OFF_V;
  float* s     = ws + OFF_S;
  float* f1    = ws + OFF_F1;
  float* f2    = ws + OFF_F2;
  float* blogt = ws + OFF_A;

  // bf16 activation planes (ushort views)
  unsigned short* h1h  = (unsigned short*)(ws + OFF_A);   // [128,32,32,96]
  unsigned short* h1l  = h1h + 12582912;
  unsigned short* mp1h = (unsigned short*)(ws + OFF_B);   // [128,16,16,96]
  unsigned short* mp1l = mp1h + 3145728;
  unsigned short* h2h  = (unsigned short*)(ws + OFF_A);   // [128,16,16,256]
  unsigned short* h2l  = h2h + 8388608;
  unsigned short* mp2h = (unsigned short*)(ws + OFF_B);   // [128,8,8,256]
  unsigned short* mp2l = mp2h + 2097152;
  unsigned short* h3h  = (unsigned short*)(ws + OFF_A);   // [128,8,8,384]
  unsigned short* h3l  = h3h + 3145728;

  // weight planes at OFF_C (dead before routing's ct is written)
  unsigned short* wc2h = (unsigned short*)(ws + OFF_C);   // [256][9][96]
  unsigned short* wc2l = wc2h + 221184;
  unsigned short* wc3h = wc2l + 221184;                   // [384][9][256]
  unsigned short* wc3l = wc3h + 884736;
  unsigned short* pwth = wc3l + 884736;                   // [256][9][384]
  unsigned short* pwtl = pwth + 884736;

  hipMemsetAsync(p,  0, (size_t)1179648 * 4, stream);
  hipMemsetAsync(f1, 0, (size_t)524288 * 4, stream);
  hipMemsetAsync(f2, 0, (size_t)524288 * 4, stream);

  // Weight transpose + bf16 split (tiny)
  wsplit_k<<<864, 256, 0, stream>>>(cw2, wc2h, wc2l, 256, 96);
  wsplit_k<<<3456, 256, 0, stream>>>(cw3, wc3h, wc3l, 384, 256);
  wsplit_k<<<3456, 256, 0, stream>>>(pw,  pwth, pwtl, 256, 384);

  // Backbone (NHWC bf16 hi/lo planes)
  conv1_k<<<dim3(512, 4), 256, 0, stream>>>(x, cw1, cb1, h1h, h1l);
  maxpool_bf<96, 32><<<12288, 256, 0, stream>>>(h1h, h1l, mp1h, mp1l);
  convgemm_nhwc<96, 16, 1, 16, false><<<dim3(4, 512), 256, 0, stream>>>(
      mp1h, mp1l, wc2h, wc2l, cb2, h2h, h2l, nullptr, 256, 1, 0);
  maxpool_bf<256, 16><<<8192, 256, 0, stream>>>(h2h, h2l, mp2h, mp2l);
  convgemm_nhwc<256, 8, 1, 8, false><<<dim3(6, 128), 256, 0, stream>>>(
      mp2h, mp2l, wc3h, wc3l, cb3, h3h, h3l, nullptr, 384, 1, 0);
  convgemm_nhwc<384, 8, 0, 6, true><<<dim3(4, 72, 2), 256, 0, stream>>>(
      h3h, h3l, pwth, pwtl, pb, nullptr, nullptr, p, 256, 0, 1728);
  squash8_k<<<576, 256, 0, stream>>>(p, pb, ut);          // u_t [1152,8,128]

  // Dynamic routing (3 iterations)
  for (int r = 0; r < 3; ++r) {
    hipMemsetAsync(s, 0, (size_t)204800 * 4, stream);
    if (r == 0) {
      caps_spass_mfma<<<dim3(100, 8), 256, 0, stream>>>(Wc, ut, ut /*dummy*/, s, 1);
    } else {
      caps_softmax<<<576, 256, 0, stream>>>(blogt, ct);
      caps_spass_mfma<<<dim3(100, 8), 256, 0, stream>>>(Wc, ut, ct, s, 0);
    }
    caps_squash16<<<50, 256, 0, stream>>>(s, v, vt);
    if (r < 2)
      caps_bupdate<<<dim3(100, 18), 256, 0, stream>>>(Wc, ut, vt, blogt, r);
  }

  // FC head; v is already [128,1600] flat
  fc_mfma<<<dim3(64, 2, 2), 256, 0, stream>>>(v,  fw1, f1, 1600, 4096, 800);
  bias_act_k<<<2048, 256, 0, stream>>>(f1, fb1, 4096, 524288, 1);
  fc_mfma<<<dim3(64, 2, 4), 256, 0, stream>>>(f1, fw2, f2, 4096, 4096, 1024);
  bias_act_k<<<2048, 256, 0, stream>>>(f2, fb2, 4096, 524288, 1);
  fc3_seed<<<100, 128, 0, stream>>>(fb3, (float*)d_out);
  fc3_sk<<<dim3(128, 4), 128, 0, stream>>>(f2, fw3, (float*)d_out);
}

// Round 4
// 1115.332 us; speedup vs baseline: 1.0137x; 1.0137x over previous
//
#include <hip/hip_runtime.h>
#include <cstddef>

// ============================================================================
// AlexCapsNet CIFAR-100 forward. Round 10: conv GEMM re-tiled to 128x128 with
// coalesced staging + XCD-bijective swizzle. Keeps round-9's pre-split bf16
// NHWC hi/lo data path (zero cvt in hot loop). LDS [row][kc] with kc^=row&3
// XOR swizzle: conflict-free staging writes AND <=2-way frag reads.
// n-major block order + XCD chunking -> one weight panel per XCD L2.
// Routing + FC head unchanged.
// ============================================================================

typedef __attribute__((ext_vector_type(8))) short bf8_t;   // 8 bf16 (4 VGPR)
typedef __attribute__((ext_vector_type(4))) float f4_t;    // 4 fp32 acc

// pack 8 fp32 -> 4 dwords of bf16-hi pairs + 4 dwords of bf16-lo pairs
__device__ inline void cvt_hilo8(const float* f, unsigned* h, unsigned* l)
{
  #pragma unroll
  for (int j = 0; j < 4; ++j) {
    unsigned u0 = __float_as_uint(f[2 * j]);
    unsigned u1 = __float_as_uint(f[2 * j + 1]);
    h[j] = (u0 >> 16) | (u1 & 0xFFFF0000u);
    float r0 = f[2 * j]     - __uint_as_float(u0 & 0xFFFF0000u);
    float r1 = f[2 * j + 1] - __uint_as_float(u1 & 0xFFFF0000u);
    l[j] = (__float_as_uint(r0) >> 16) | (__float_as_uint(r1) & 0xFFFF0000u);
  }
}

// truncating hi/lo split of one fp32 (same math as cvt_hilo8)
__device__ inline void split1(float f, unsigned short& h, unsigned short& l)
{
  unsigned u = __float_as_uint(f);
  h = (unsigned short)(u >> 16);
  float r = f - __uint_as_float(u & 0xFFFF0000u);
  l = (unsigned short)(__float_as_uint(r) >> 16);
}

__device__ inline float bf2f(unsigned short h, unsigned short l)
{
  return __uint_as_float((unsigned)h << 16) + __uint_as_float((unsigned)l << 16);
}

// bijective XCD chunking (m204): consecutive logical ids land on one XCD
__device__ inline int xcd_swz(int bid, int nwg)
{
  int xcd = bid & 7, pos = bid >> 3;
  int q = nwg >> 3, r = nwg & 7;
  return (xcd < r ? xcd * (q + 1) : r * (q + 1) + (xcd - r) * q) + pos;
}

// ---------- weight transpose+split: w[co][ci][r9] f32 -> [co][r9][ci] bf16 hi/lo
__global__ __launch_bounds__(256) void wsplit_k(
    const float* __restrict__ w, unsigned short* __restrict__ oh,
    unsigned short* __restrict__ ol, int CO, int CI)
{
  int idx = blockIdx.x * 256 + threadIdx.x;          // grid sized exactly
  int ci = idx % CI;
  int t2 = idx / CI;
  int r = t2 % 9, co = t2 / 9;
  float f = w[((size_t)co * CI + ci) * 9 + r];
  unsigned short h, l;
  split1(f, h, l);
  oh[idx] = h; ol[idx] = l;
}

// ---------- conv1: 3->96 k3 s1 p1 + relu -> NHWC bf16 hi/lo ----------
__global__ __launch_bounds__(256) void conv1_k(
    const float* __restrict__ x, const float* __restrict__ wt,
    const float* __restrict__ bias, unsigned short* __restrict__ oh,
    unsigned short* __restrict__ ol)
{
  int idx = blockIdx.x * 256 + threadIdx.x;     // (b, h, w)
  int w = idx & 31, h = (idx >> 5) & 31, b = idx >> 10;
  int co0 = blockIdx.y * 24;                    // co-slice

  float xv[27];
  const float* xb = x + (size_t)b * 3072;
  #pragma unroll
  for (int ci = 0; ci < 3; ++ci)
    #pragma unroll
    for (int dh = 0; dh < 3; ++dh) {
      int ih = h + dh - 1;
      #pragma unroll
      for (int dw = 0; dw < 3; ++dw) {
        int iw = w + dw - 1;
        bool ok = ((unsigned)ih < 32u) & ((unsigned)iw < 32u);
        xv[ci * 9 + dh * 3 + dw] = ok ? xb[(ci << 10) + (ih << 5) + iw] : 0.f;
      }
    }

  size_t obase = ((size_t)b * 1024 + (h << 5) + w) * 96 + co0;
  const float* wp = wt + (size_t)co0 * 27;      // wave-uniform -> s_load
  #pragma unroll 2
  for (int cp = 0; cp < 12; ++cp) {
    float a0 = bias[co0 + 2 * cp], a1 = bias[co0 + 2 * cp + 1];
    #pragma unroll
    for (int k = 0; k < 27; ++k) {
      a0 += xv[k] * wp[(2 * cp) * 27 + k];
      a1 += xv[k] * wp[(2 * cp + 1) * 27 + k];
    }
    a0 = fmaxf(a0, 0.f); a1 = fmaxf(a1, 0.f);
    unsigned short h0, l0, h1, l1;
    split1(a0, h0, l0); split1(a1, h1, l1);
    *(unsigned*)(oh + obase + 2 * cp) = (unsigned)h0 | ((unsigned)h1 << 16);
    *(unsigned*)(ol + obase + 2 * cp) = (unsigned)l0 | ((unsigned)l1 << 16);
  }
}

// ---------- maxpool k3 s2 p1 on NHWC bf16 hi/lo pairs ----------
template <int C, int H>
__global__ __launch_bounds__(256) void maxpool_bf(
    const unsigned short* __restrict__ inh, const unsigned short* __restrict__ inl,
    unsigned short* __restrict__ outh, unsigned short* __restrict__ outl)
{
  constexpr int Ho = H >> 1;
  int idx = blockIdx.x * 256 + threadIdx.x;
  int c = idx % C;
  int q = idx / C;
  int wo = q % Ho;
  int q2 = q / Ho;
  int ho = q2 % Ho, b = q2 / Ho;
  float best = -3.4e38f;
  unsigned short bh = 0, bl = 0;
  #pragma unroll
  for (int dh = 0; dh < 3; ++dh) {
    int ih = 2 * ho - 1 + dh;
    if ((unsigned)ih >= (unsigned)H) continue;
    #pragma unroll
    for (int dw = 0; dw < 3; ++dw) {
      int iw = 2 * wo - 1 + dw;
      if ((unsigned)iw >= (unsigned)H) continue;
      size_t off = ((size_t)(b * H + ih) * H + iw) * C + c;
      unsigned short uh = inh[off], ul = inl[off];
      float f = bf2f(uh, ul);
      if (f > best) { best = f; bh = uh; bl = ul; }
    }
  }
  outh[idx] = bh; outl[idx] = bl;
}

// ---------- conv as 128x128-tile MFMA GEMM, NHWC bf16 hi/lo ----------
// A = pixels (M), B = weights (N = CO). K order (dh,dw,ci), CI%32==0 so each
// 32-k step sits in one (dh,dw). Staging: thread t loads row t>>2, kchunk t&3
// (contiguous 64B rows). LDS [rg][row][kc], kc XOR row&3.
template <int CI, int H, int PAD, int WO, int CO, int MT, bool SPLIT>
__global__ __launch_bounds__(256) void conv128(
    const unsigned short* __restrict__ inh, const unsigned short* __restrict__ inl,
    const unsigned short* __restrict__ wh, const unsigned short* __restrict__ wl,
    const float* __restrict__ bias, unsigned short* __restrict__ outh,
    unsigned short* __restrict__ outl, float* __restrict__ outf,
    int relu, int KC)
{
  constexpr int K = CI * 9;
  constexpr int NPIX = WO * WO;
  __shared__ uint4 Ah[512], Al[512], Bh[512], Bl[512];   // 32KB

  int id = xcd_swz(blockIdx.x, gridDim.x);
  int ntile = id / MT, mtile = id - ntile * MT;
  int n0 = ntile * 128, m0 = mtile * 128;
  int kbeg = SPLIT ? blockIdx.z * KC : 0;
  int kend = SPLIT ? kbeg + KC : K;

  int t = threadIdx.x;
  int lane = t & 63;
  int wave = __builtin_amdgcn_readfirstlane(t >> 6);
  int wm = wave & 1, wn = wave >> 1;
  int lr = lane & 15, lq = lane >> 4;

  // staging roles
  int srow = (t >> 2) & 63;                  // row within 64-group
  int kc8 = (t & 3) * 8;                     // k offset within 32-chunk
  int sidx = srow * 4 + ((t & 3) ^ (srow & 3));

  // A-side pixel geometry for both row-groups
  int ih0g[2], iw0g[2];
  size_t ibaseg[2];
  #pragma unroll
  for (int g = 0; g < 2; ++g) {
    int pix = m0 + g * 64 + srow;
    int bpix = pix / NPIX, xy = pix - bpix * NPIX;
    int ho = xy / WO, wo = xy - ho * WO;
    ih0g[g] = ho - PAD; iw0g[g] = wo - PAD;
    ibaseg[g] = (size_t)bpix * H * H;
  }

  uint4 pah[2], pal_[2], pbh[2], pbl[2];
  auto loadA = [&](int k0) {
    int r = k0 / CI;
    int cib = k0 - r * CI + kc8;
    int dh = r / 3, dw = r - dh * 3;
    #pragma unroll
    for (int g = 0; g < 2; ++g) {
      int ih = ih0g[g] + dh, iw = iw0g[g] + dw;
      bool ok = ((unsigned)ih < (unsigned)H) & ((unsigned)iw < (unsigned)H);
      if (ok) {
        size_t ad = (ibaseg[g] + (size_t)ih * H + iw) * CI + cib;
        pah[g] = *(const uint4*)(inh + ad);
        pal_[g] = *(const uint4*)(inl + ad);
      } else {
        pah[g] = make_uint4(0u, 0u, 0u, 0u);
        pal_[g] = make_uint4(0u, 0u, 0u, 0u);
      }
    }
  };
  auto loadB = [&](int k0) {
    #pragma unroll
    for (int g = 0; g < 2; ++g) {
      size_t ad = (size_t)(n0 + g * 64 + srow) * K + k0 + kc8;
      pbh[g] = *(const uint4*)(wh + ad);
      pbl[g] = *(const uint4*)(wl + ad);
    }
  };

  loadA(kbeg); loadB(kbeg);
  f4_t acc[4][4];
  #pragma unroll
  for (int mt = 0; mt < 4; ++mt)
    #pragma unroll
    for (int nt = 0; nt < 4; ++nt) acc[mt][nt] = (f4_t)0.0f;

  for (int k0 = kbeg; k0 < kend; k0 += 32) {
    if (k0 > kbeg) __syncthreads();
    Ah[sidx] = pah[0]; Ah[256 + sidx] = pah[1];
    Al[sidx] = pal_[0]; Al[256 + sidx] = pal_[1];
    Bh[sidx] = pbh[0]; Bh[256 + sidx] = pbh[1];
    Bl[sidx] = pbl[0]; Bl[256 + sidx] = pbl[1];
    __syncthreads();
    if (k0 + 32 < kend) { loadA(k0 + 32); loadB(k0 + 32); }

    int xk = lq ^ (lr & 3);
    int aBase = wm * 256 + lr * 4 + xk;
    int bBase = wn * 256 + lr * 4 + xk;
    bf8_t bvh[4], bvl[4];
    #pragma unroll
    for (int nt = 0; nt < 4; ++nt) {
      bvh[nt] = *(const bf8_t*)&Bh[bBase + nt * 64];
      bvl[nt] = *(const bf8_t*)&Bl[bBase + nt * 64];
    }
    #pragma unroll
    for (int mt = 0; mt < 4; ++mt) {
      bf8_t avh = *(const bf8_t*)&Ah[aBase + mt * 64];
      bf8_t avl = *(const bf8_t*)&Al[aBase + mt * 64];
      #pragma unroll
      for (int nt = 0; nt < 4; ++nt) {
        acc[mt][nt] = __builtin_amdgcn_mfma_f32_16x16x32_bf16(avh, bvh[nt], acc[mt][nt], 0, 0, 0);
        acc[mt][nt] = __builtin_amdgcn_mfma_f32_16x16x32_bf16(avh, bvl[nt], acc[mt][nt], 0, 0, 0);
        acc[mt][nt] = __builtin_amdgcn_mfma_f32_16x16x32_bf16(avl, bvh[nt], acc[mt][nt], 0, 0, 0);
      }
    }
  }

  // D: row = pixel m, col = co n; NHWC flat m*CO + n
  #pragma unroll
  for (int mt = 0; mt < 4; ++mt)
    #pragma unroll
    for (int nt = 0; nt < 4; ++nt) {
      #pragma unroll
      for (int r = 0; r < 4; ++r) {
        int m = m0 + wm * 64 + mt * 16 + lq * 4 + r;
        int n = n0 + wn * 64 + nt * 16 + lr;
        size_t oidx = (size_t)m * CO + n;
        if (SPLIT) {
          atomicAdd(outf + oidx, acc[mt][nt][r]);
        } else {
          float vv = acc[mt][nt][r] + bias[n];
          if (relu) vv = fmaxf(vv, 0.f);
          unsigned short h, l;
          split1(vv, h, l);
          outh[oidx] = h; outl[oidx] = l;
        }
      }
    }
}

// ---------- FC as bf16x2-split MFMA GEMM, split-K, atomic partials ----------
__global__ __launch_bounds__(256) void fc_mfma(
    const float* __restrict__ A, const float* __restrict__ W,
    float* __restrict__ C, int K, int N, int KC)
{
  __shared__ uint4 Ah[256], Al[256], Bh[256], Bl[256];
  int n0 = blockIdx.x * 64, m0 = blockIdx.y * 64;
  int kbeg = blockIdx.z * KC, kend = kbeg + KC;
  int t = threadIdx.x;
  int lane = t & 63;
  int wave = __builtin_amdgcn_readfirstlane(t >> 6);
  int wm = wave & 1, wn = wave >> 1;
  int lr = lane & 15, lq = lane >> 4;
  int smA = t >> 2, sgA = t & 3;

  float fa[8], fb[8];
  auto loadA = [&](int k0) {
    const float4* ap = (const float4*)(A + (size_t)(m0 + smA) * K + k0 + sgA * 8);
    float4 a0 = ap[0], a1 = ap[1];
    fa[0] = a0.x; fa[1] = a0.y; fa[2] = a0.z; fa[3] = a0.w;
    fa[4] = a1.x; fa[5] = a1.y; fa[6] = a1.z; fa[7] = a1.w;
  };
  auto loadB = [&](int k0) {
    const float* wp = W + (size_t)(k0 + wave * 8) * N + n0 + lane;
    #pragma unroll
    for (int j = 0; j < 8; ++j) fb[j] = wp[(size_t)j * N];
  };

  loadA(kbeg); loadB(kbeg);
  f4_t acc[2][2];
  #pragma unroll
  for (int mt = 0; mt < 2; ++mt)
    #pragma unroll
    for (int nt = 0; nt < 2; ++nt) acc[mt][nt] = (f4_t)0.0f;

  for (int k0 = kbeg; k0 < kend; k0 += 32) {
    if (k0 > kbeg) __syncthreads();
    unsigned ha[4], la[4], hb[4], lb[4];
    cvt_hilo8(fa, ha, la);
    cvt_hilo8(fb, hb, lb);
    Ah[sgA * 64 + smA] = make_uint4(ha[0], ha[1], ha[2], ha[3]);
    Al[sgA * 64 + smA] = make_uint4(la[0], la[1], la[2], la[3]);
    Bh[wave * 64 + lane] = make_uint4(hb[0], hb[1], hb[2], hb[3]);
    Bl[wave * 64 + lane] = make_uint4(lb[0], lb[1], lb[2], lb[3]);
    __syncthreads();
    if (k0 + 32 < kend) { loadA(k0 + 32); loadB(k0 + 32); }
    bf8_t av_h[2], av_l[2], bv_h[2], bv_l[2];
    #pragma unroll
    for (int mt = 0; mt < 2; ++mt) {
      int ui = lq * 64 + wm * 32 + mt * 16 + lr;
      av_h[mt] = *(const bf8_t*)&Ah[ui];
      av_l[mt] = *(const bf8_t*)&Al[ui];
    }
    #pragma unroll
    for (int nt = 0; nt < 2; ++nt) {
      int ui = lq * 64 + wn * 32 + nt * 16 + lr;
      bv_h[nt] = *(const bf8_t*)&Bh[ui];
      bv_l[nt] = *(const bf8_t*)&Bl[ui];
    }
    #pragma unroll
    for (int mt = 0; mt < 2; ++mt)
      #pragma unroll
      for (int nt = 0; nt < 2; ++nt) {
        acc[mt][nt] = __builtin_amdgcn_mfma_f32_16x16x32_bf16(av_h[mt], bv_h[nt], acc[mt][nt], 0, 0, 0);
        acc[mt][nt] = __builtin_amdgcn_mfma_f32_16x16x32_bf16(av_h[mt], bv_l[nt], acc[mt][nt], 0, 0, 0);
        acc[mt][nt] = __builtin_amdgcn_mfma_f32_16x16x32_bf16(av_l[mt], bv_h[nt], acc[mt][nt], 0, 0, 0);
      }
  }
  #pragma unroll
  for (int mt = 0; mt < 2; ++mt)
    #pragma unroll
    for (int nt = 0; nt < 2; ++nt) {
      #pragma unroll
      for (int r = 0; r < 4; ++r) {
        int m = m0 + wm * 32 + mt * 16 + lq * 4 + r;
        int n = n0 + wn * 32 + nt * 16 + lr;
        atomicAdd(C + (size_t)m * N + n, acc[mt][nt][r]);
      }
    }
}

// ---------- squash8 + pcaps bias; p[b,pix36,co256] NHWC -> u_t[i,e,b] ----------
__global__ __launch_bounds__(256) void squash8_k(
    const float* __restrict__ p, const float* __restrict__ pb,
    float* __restrict__ ut)
{
  int idx = blockIdx.x * 256 + threadIdx.x;
  if (idx >= 147456) return;
  int b = idx & 127, i = idx >> 7;
  float pv[8];
  #pragma unroll
  for (int e = 0; e < 8; ++e) {
    int f = i * 8 + e;
    int co = f / 36, pix = f - co * 36;
    pv[e] = p[((size_t)b * 36 + pix) * 256 + co] + pb[co];
  }
  float n2 = 0.f;
  #pragma unroll
  for (int e = 0; e < 8; ++e) n2 += pv[e] * pv[e];
  float sc = (n2 / (1.f + n2)) * rsqrtf(n2 + 1e-8f);
  #pragma unroll
  for (int e = 0; e < 8; ++e)
    ut[(size_t)i * 1024 + e * 128 + b] = pv[e] * sc;
}

// ---------- squash16: s[b,o,16] -> v[b,o,16] + v_t[o,d,b] ----------
__global__ __launch_bounds__(256) void caps_squash16(
    const float* __restrict__ s, float* __restrict__ v, float* __restrict__ vt)
{
  int idx = blockIdx.x * 256 + threadIdx.x;
  if (idx >= 12800) return;
  int b = idx / 100, o = idx % 100;
  const float4* sp = (const float4*)(s + (size_t)idx * 16);
  float4 a = sp[0], bb = sp[1], c = sp[2], d = sp[3];
  float n2 = a.x * a.x + a.y * a.y + a.z * a.z + a.w * a.w +
             bb.x * bb.x + bb.y * bb.y + bb.z * bb.z + bb.w * bb.w +
             c.x * c.x + c.y * c.y + c.z * c.z + c.w * c.w +
             d.x * d.x + d.y * d.y + d.z * d.z + d.w * d.w;
  float sc = (n2 / (1.f + n2)) * rsqrtf(n2 + 1e-8f);
  float vv[16] = {a.x, a.y, a.z, a.w, bb.x, bb.y, bb.z, bb.w,
                  c.x, c.y, c.z, c.w, d.x, d.y, d.z, d.w};
  float4* vp = (float4*)(v + (size_t)idx * 16);
  float4 o0 = {vv[0] * sc, vv[1] * sc, vv[2] * sc, vv[3] * sc};
  float4 o1 = {vv[4] * sc, vv[5] * sc, vv[6] * sc, vv[7] * sc};
  float4 o2 = {vv[8] * sc, vv[9] * sc, vv[10] * sc, vv[11] * sc};
  float4 o3 = {vv[12] * sc, vv[13] * sc, vv[14] * sc, vv[15] * sc};
  vp[0] = o0; vp[1] = o1; vp[2] = o2; vp[3] = o3;
  #pragma unroll
  for (int dd = 0; dd < 16; ++dd)
    vt[((size_t)o * 16 + dd) * 128 + b] = vv[dd] * sc;
}

// ---------- routing s-pass as per-o MFMA GEMM ----------
__global__ __launch_bounds__(256) void caps_spass_mfma(
    const float* __restrict__ W, const float* __restrict__ ut,
    const float* __restrict__ ct, float* __restrict__ s, int uniform)
{
  __shared__ uint4 Ah[512], Al[512];               // [quad(4)][b(128)] 8KB each
  int o = blockIdx.x, ks = blockIdx.y;
  int t = threadIdx.x;
  int lane = t & 63;
  int wave = __builtin_amdgcn_readfirstlane(t >> 6);
  int lr = lane & 15, lq = lane >> 4;
  int b = t & 127, half = t >> 7;                  // staging role
  int i0 = ks * 144;

  float fu[16], fc[2], fw[8];
  auto loadUC = [&](int j) {
    int ib = i0 + j * 4 + half * 2;
    #pragma unroll
    for (int q = 0; q < 2; ++q) {
      int i = ib + q;
      #pragma unroll
      for (int e = 0; e < 8; ++e)
        fu[q * 8 + e] = ut[(size_t)i * 1024 + e * 128 + b];   // coalesced
      fc[q] = uniform ? 0.01f : ct[((size_t)o * 1152 + i) * 128 + b];
    }
  };
  auto loadW = [&](int j) {
    int i = i0 + j * 4 + lq;
    const float4* wp = (const float4*)(W + (((size_t)o * 1152 + i) * 16 + lr) * 8);
    float4 w0 = wp[0], w1 = wp[1];
    fw[0] = w0.x; fw[1] = w0.y; fw[2] = w0.z; fw[3] = w0.w;
    fw[4] = w1.x; fw[5] = w1.y; fw[6] = w1.z; fw[7] = w1.w;
  };

  loadUC(0); loadW(0);
  f4_t acc[2];
  acc[0] = (f4_t)0.0f; acc[1] = (f4_t)0.0f;

  for (int j = 0; j < 36; ++j) {
    float cu[16];
    #pragma unroll
    for (int q = 0; q < 2; ++q)
      #pragma unroll
      for (int e = 0; e < 8; ++e)
        cu[q * 8 + e] = fc[q] * fu[q * 8 + e];
    unsigned h0[4], l0[4], h1[4], l1[4], wh[4], wl[4];
    cvt_hilo8(cu, h0, l0);
    cvt_hilo8(cu + 8, h1, l1);
    cvt_hilo8(fw, wh, wl);                          // current W split (before prefetch)
    uint4 uwh = make_uint4(wh[0], wh[1], wh[2], wh[3]);
    uint4 uwl = make_uint4(wl[0], wl[1], wl[2], wl[3]);
    bf8_t bfh = *(const bf8_t*)&uwh;
    bf8_t bfl = *(const bf8_t*)&uwl;
    if (j > 0) __syncthreads();
    Ah[(half * 2 + 0) * 128 + b] = make_uint4(h0[0], h0[1], h0[2], h0[3]);
    Al[(half * 2 + 0) * 128 + b] = make_uint4(l0[0], l0[1], l0[2], l0[3]);
    Ah[(half * 2 + 1) * 128 + b] = make_uint4(h1[0], h1[1], h1[2], h1[3]);
    Al[(half * 2 + 1) * 128 + b] = make_uint4(l1[0], l1[1], l1[2], l1[3]);
    __syncthreads();
    if (j + 1 < 36) { loadUC(j + 1); loadW(j + 1); }
    #pragma unroll
    for (int mt = 0; mt < 2; ++mt) {
      int bidx = wave * 16 + mt * 64 + lr;
      bf8_t avh = *(const bf8_t*)&Ah[lq * 128 + bidx];
      bf8_t avl = *(const bf8_t*)&Al[lq * 128 + bidx];
      acc[mt] = __builtin_amdgcn_mfma_f32_16x16x32_bf16(avh, bfh, acc[mt], 0, 0, 0);
      acc[mt] = __builtin_amdgcn_mfma_f32_16x16x32_bf16(avh, bfl, acc[mt], 0, 0, 0);
      acc[mt] = __builtin_amdgcn_mfma_f32_16x16x32_bf16(avl, bfh, acc[mt], 0, 0, 0);
    }
  }
  // D layout: col(d)=lane&15, row(b)=lq*4+r
  #pragma unroll
  for (int mt = 0; mt < 2; ++mt)
    #pragma unroll
    for (int r = 0; r < 4; ++r) {
      int bb = wave * 16 + mt * 64 + lq * 4 + r;
      atomicAdd(s + ((size_t)bb * 100 + o) * 16 + lr, acc[mt][r]);
    }
}

// ---------- routing b-update as MFMA ----------
__global__ __launch_bounds__(256) void caps_bupdate(
    const float* __restrict__ W, const float* __restrict__ ut,
    const float* __restrict__ vt, float* __restrict__ blogt, int accum)
{
  __shared__ __align__(16) float Wt[64 * 160];   // [li][e(stride 20)][d] 40KB
  int o = blockIdx.x, ic = blockIdx.y;
  int t = threadIdx.x;
  int lane = t & 63;
  int wave = __builtin_amdgcn_readfirstlane(t >> 6);
  int lr = lane & 15, lq = lane >> 4;
  int dhalf = (lq & 1) << 3;        // which 8 d's this lq-quarter covers
  int hl = lq >> 1;                 // 0: hi plane (k<16), 1: lo plane (k>=16)

  {
    const float4* Wg = (const float4*)(W + ((size_t)o * 1152 + (size_t)ic * 64) * 128);
    for (int l = t; l < 2048; l += 256) {
      float4 w = Wg[l];
      int li = l >> 5;
      int rem = l & 31;
      int d = rem >> 1;
      int e0 = (rem & 1) << 2;
      float* dst = &Wt[li * 160 + e0 * 20 + d];
      dst[0] = w.x; dst[20] = w.y; dst[40] = w.z; dst[60] = w.w;
    }
  }

  bf8_t B1[8], B2[8];
  #pragma unroll
  for (int nt = 0; nt < 8; ++nt) {
    int b = nt * 16 + lr;
    float vv[8];
    #pragma unroll
    for (int j = 0; j < 8; ++j)
      vv[j] = vt[((size_t)o * 16 + dhalf + j) * 128 + b];
    unsigned h[4], l2[4];
    cvt_hilo8(vv, h, l2);
    uint4 uh = make_uint4(h[0], h[1], h[2], h[3]);
    uint4 ul = (lq < 2) ? make_uint4(l2[0], l2[1], l2[2], l2[3])
                        : make_uint4(0u, 0u, 0u, 0u);
    B1[nt] = *(const bf8_t*)&uh;
    B2[nt] = *(const bf8_t*)&ul;
  }
  __syncthreads();

  unsigned lomask = hl ? 0xFFFF0000u : 0u;

  for (int mi = 0; mi < 8; ++mi) {
    int mt = wave * 8 + mi;
    int liA = mt * 2 + (lr >> 3);
    int eA = lr & 7;
    const float* wp = &Wt[liA * 160 + eA * 20 + dhalf];
    float4 wa = *(const float4*)wp;
    float4 wb = *(const float4*)(wp + 4);
    float fw[8] = {wa.x, wa.y, wa.z, wa.w, wb.x, wb.y, wb.z, wb.w};
    unsigned ha[4];
    #pragma unroll
    for (int j = 0; j < 4; ++j) {
      float f0 = fw[2 * j], f1 = fw[2 * j + 1];
      f0 -= __uint_as_float(__float_as_uint(f0) & lomask);
      f1 -= __uint_as_float(__float_as_uint(f1) & lomask);
      ha[j] = (__float_as_uint(f0) >> 16) | (__float_as_uint(f1) & 0xFFFF0000u);
    }
    uint4 ua = make_uint4(ha[0], ha[1], ha[2], ha[3]);
    bf8_t A = *(const bf8_t*)&ua;

    int gi = ic * 64 + mt * 2 + hl;
    const float* up = ut + (size_t)gi * 1024 + (size_t)(((lq & 1) << 2)) * 128;
    #pragma unroll
    for (int nt = 0; nt < 8; ++nt) {
      f4_t acc = (f4_t)0.0f;
      acc = __builtin_amdgcn_mfma_f32_16x16x32_bf16(A, B1[nt], acc, 0, 0, 0);
      acc = __builtin_amdgcn_mfma_f32_16x16x32_bf16(A, B2[nt], acc, 0, 0, 0);
      int b = nt * 16 + lr;
      float p = acc[0] * up[b] + acc[1] * up[128 + b] +
                acc[2] * up[256 + b] + acc[3] * up[384 + b];
      p += __shfl_xor(p, 16);
      if (!(lq & 1)) {
        size_t off = ((size_t)o * 1152 + gi) * 128 + b;
        if (accum) blogt[off] += p; else blogt[off] = p;
      }
    }
  }
}

// ---------- softmax over o per (i,b), transposed layouts ----------
__global__ __launch_bounds__(256) void caps_softmax(
    const float* __restrict__ blogt, float* __restrict__ ct)
{
  int idx = blockIdx.x * 256 + threadIdx.x;
  if (idx >= 147456) return;
  const float* bp = blogt + idx;
  float m = -3.4e38f;
  for (int o = 0; o < 100; ++o) m = fmaxf(m, bp[(size_t)o * 147456]);
  float sum = 0.f;
  for (int o = 0; o < 100; ++o) sum += __expf(bp[(size_t)o * 147456] - m);
  float inv = 1.f / sum;
  for (int o = 0; o < 100; ++o)
    ct[(size_t)o * 147456 + idx] = __expf(bp[(size_t)o * 147456] - m) * inv;
}

// ---------- bias + optional relu, in place ----------
__global__ __launch_bounds__(256) void bias_act_k(
    float* __restrict__ C, const float* __restrict__ bias, int N, int total, int relu)
{
  int idx = blockIdx.x * 256 + threadIdx.x;
  if (idx >= total) return;
  float vv = C[idx] + bias[idx % N];
  if (relu) vv = fmaxf(vv, 0.f);
  C[idx] = vv;
}

// ---------- fc3 ----------
__global__ __launch_bounds__(128) void fc3_seed(
    const float* __restrict__ bias, float* __restrict__ out)
{
  int idx = blockIdx.x * 128 + threadIdx.x;
  if (idx < 12800) out[idx] = bias[idx % 100];
}

__global__ __launch_bounds__(128) void fc3_sk(
    const float* __restrict__ A, const float* __restrict__ W,
    float* __restrict__ out)
{
  __shared__ float Al[1024];
  int m = blockIdx.x, z = blockIdx.y, t = threadIdx.x;
  int kbeg = z * 1024;
  const float* ap = A + (size_t)m * 4096 + kbeg;
  for (int l = t; l < 1024; l += 128) Al[l] = ap[l];
  __syncthreads();
  if (t < 100) {
    float acc = 0.f;
    const float* wp = W + (size_t)kbeg * 100 + t;
    #pragma unroll 8
    for (int k = 0; k < 1024; ++k) acc += Al[k] * wp[(size_t)k * 100];
    atomicAdd(out + m * 100 + t, acc);
  }
}

// ============================================================================
extern "C" void kernel_launch(void* const* d_in, const int* in_sizes, int n_in,
                              void* d_out, int out_size, void* d_ws, size_t ws_size,
                              hipStream_t stream)
{
  (void)in_sizes; (void)n_in; (void)out_size; (void)ws_size;
  const float* x   = (const float*)d_in[0];
  const float* cw1 = (const float*)d_in[1];
  const float* cb1 = (const float*)d_in[2];
  const float* cw2 = (const float*)d_in[3];
  const float* cb2 = (const float*)d_in[4];
  const float* cw3 = (const float*)d_in[5];
  const float* cb3 = (const float*)d_in[6];
  const float* pw  = (const float*)d_in[7];
  const float* pb  = (const float*)d_in[8];
  const float* Wc  = (const float*)d_in[9];
  const float* fw1 = (const float*)d_in[10];
  const float* fb1 = (const float*)d_in[11];
  const float* fw2 = (const float*)d_in[12];
  const float* fb2 = (const float*)d_in[13];
  const float* fw3 = (const float*)d_in[14];
  const float* fb3 = (const float*)d_in[15];
  float* ws = (float*)d_ws;

  const size_t OFF_A  = 0;          // act planes; later blog_t [o,i,b]
  const size_t OFF_B  = 12582912;   // pooled planes
  const size_t OFF_U  = 15728640;   // u_t [1152,8,128]
  const size_t OFF_P  = 16908288;   // p [128,36,256] NHWC; later v_t [100,16,128]
  const size_t OFF_C  = 18087936;   // weight planes (backbone) / c_t (routing)
  const size_t OFF_V  = 32833536;   // v [128,100,16]
  const size_t OFF_S  = 33038336;   // s [128,100,16]
  const size_t OFF_F1 = 33243136;   // f1 [128,4096]
  const size_t OFF_F2 = 33767424;   // f2 [128,4096]

  float* ut    = ws + OFF_U;
  float* p     = ws + OFF_P;
  float* vt    = ws + OFF_P;        // reuses p region after squash8
  float* ct    = ws + OFF_C;
  float* v     = ws + OFF_V;
  float* s     = ws + OFF_S;
  float* f1    = ws + OFF_F1;
  float* f2    = ws + OFF_F2;
  float* blogt = ws + OFF_A;

  // bf16 activation planes (ushort views)
  unsigned short* h1h  = (unsigned short*)(ws + OFF_A);   // [128,32,32,96]
  unsigned short* h1l  = h1h + 12582912;
  unsigned short* mp1h = (unsigned short*)(ws + OFF_B);   // [128,16,16,96]
  unsigned short* mp1l = mp1h + 3145728;
  unsigned short* h2h  = (unsigned short*)(ws + OFF_A);   // [128,16,16,256]
  unsigned short* h2l  = h2h + 8388608;
  unsigned short* mp2h = (unsigned short*)(ws + OFF_B);   // [128,8,8,256]
  unsigned short* mp2l = mp2h + 2097152;
  unsigned short* h3h  = (unsigned short*)(ws + OFF_A);   // [128,8,8,384]
  unsigned short* h3l  = h3h + 3145728;

  // weight planes at OFF_C (dead before routing's ct is written)
  unsigned short* wc2h = (unsigned short*)(ws + OFF_C);   // [256][9][96]
  unsigned short* wc2l = wc2h + 221184;
  unsigned short* wc3h = wc2l + 221184;                   // [384][9][256]
  unsigned short* wc3l = wc3h + 884736;
  unsigned short* pwth = wc3l + 884736;                   // [256][9][384]
  unsigned short* pwtl = pwth + 884736;

  hipMemsetAsync(p,  0, (size_t)1179648 * 4, stream);
  hipMemsetAsync(f1, 0, (size_t)524288 * 4, stream);
  hipMemsetAsync(f2, 0, (size_t)524288 * 4, stream);

  // Weight transpose + bf16 split (tiny)
  wsplit_k<<<864, 256, 0, stream>>>(cw2, wc2h, wc2l, 256, 96);
  wsplit_k<<<3456, 256, 0, stream>>>(cw3, wc3h, wc3l, 384, 256);
  wsplit_k<<<3456, 256, 0, stream>>>(pw,  pwth, pwtl, 256, 384);

  // Backbone (NHWC bf16 hi/lo planes)
  conv1_k<<<dim3(512, 4), 256, 0, stream>>>(x, cw1, cb1, h1h, h1l);
  maxpool_bf<96, 32><<<12288, 256, 0, stream>>>(h1h, h1l, mp1h, mp1l);
  conv128<96, 16, 1, 16, 256, 256, false><<<512, 256, 0, stream>>>(
      mp1h, mp1l, wc2h, wc2l, cb2, h2h, h2l, nullptr, 1, 0);
  maxpool_bf<256, 16><<<8192, 256, 0, stream>>>(h2h, h2l, mp2h, mp2l);
  conv128<256, 8, 1, 8, 384, 64, false><<<192, 256, 0, stream>>>(
      mp2h, mp2l, wc3h, wc3l, cb3, h3h, h3l, nullptr, 1, 0);
  conv128<384, 8, 0, 6, 256, 36, true><<<dim3(72, 1, 4), 256, 0, stream>>>(
      h3h, h3l, pwth, pwtl, pb, nullptr, nullptr, p, 0, 864);
  squash8_k<<<576, 256, 0, stream>>>(p, pb, ut);          // u_t [1152,8,128]

  // Dynamic routing (3 iterations)
  for (int r = 0; r < 3; ++r) {
    hipMemsetAsync(s, 0, (size_t)204800 * 4, stream);
    if (r == 0) {
      caps_spass_mfma<<<dim3(100, 8), 256, 0, stream>>>(Wc, ut, ut /*dummy*/, s, 1);
    } else {
      caps_softmax<<<576, 256, 0, stream>>>(blogt, ct);
      caps_spass_mfma<<<dim3(100, 8), 256, 0, stream>>>(Wc, ut, ct, s, 0);
    }
    caps_squash16<<<50, 256, 0, stream>>>(s, v, vt);
    if (r < 2)
      caps_bupdate<<<dim3(100, 18), 256, 0, stream>>>(Wc, ut, vt, blogt, r);
  }

  // FC head; v is already [128,1600] flat
  fc_mfma<<<dim3(64, 2, 2), 256, 0, stream>>>(v,  fw1, f1, 1600, 4096, 800);
  bias_act_k<<<2048, 256, 0, stream>>>(f1, fb1, 4096, 524288, 1);
  fc_mfma<<<dim3(64, 2, 4), 256, 0, stream>>>(f1, fw2, f2, 4096, 4096, 1024);
  bias_act_k<<<2048, 256, 0, stream>>>(f2, fb2, 4096, 524288, 1);
  fc3_seed<<<100, 128, 0, stream>>>(fb3, (float*)d_out);
  fc3_sk<<<dim3(128, 4), 128, 0, stream>>>(f2, fw3, (float*)d_out);
}

// Round 5
// 1094.750 us; speedup vs baseline: 1.0327x; 1.0188x over previous
//
#include <hip/hip_runtime.h>
#include <cstddef>

// ============================================================================
// AlexCapsNet CIFAR-100 forward. Round 11: fix conv3/pcaps parallelism
// starvation (192/288 blocks on 256 CUs -> occupancy 8%). conv3 now split-K
// z=4 (768 blocks) with fp32 atomic accum + fused bias/relu/split pass;
// pcaps z=6 (432 blocks). conv GEMM structure unchanged from round 10.
// ============================================================================

typedef __attribute__((ext_vector_type(8))) short bf8_t;   // 8 bf16 (4 VGPR)
typedef __attribute__((ext_vector_type(4))) float f4_t;    // 4 fp32 acc

// pack 8 fp32 -> 4 dwords of bf16-hi pairs + 4 dwords of bf16-lo pairs
__device__ inline void cvt_hilo8(const float* f, unsigned* h, unsigned* l)
{
  #pragma unroll
  for (int j = 0; j < 4; ++j) {
    unsigned u0 = __float_as_uint(f[2 * j]);
    unsigned u1 = __float_as_uint(f[2 * j + 1]);
    h[j] = (u0 >> 16) | (u1 & 0xFFFF0000u);
    float r0 = f[2 * j]     - __uint_as_float(u0 & 0xFFFF0000u);
    float r1 = f[2 * j + 1] - __uint_as_float(u1 & 0xFFFF0000u);
    l[j] = (__float_as_uint(r0) >> 16) | (__float_as_uint(r1) & 0xFFFF0000u);
  }
}

// truncating hi/lo split of one fp32 (same math as cvt_hilo8)
__device__ inline void split1(float f, unsigned short& h, unsigned short& l)
{
  unsigned u = __float_as_uint(f);
  h = (unsigned short)(u >> 16);
  float r = f - __uint_as_float(u & 0xFFFF0000u);
  l = (unsigned short)(__float_as_uint(r) >> 16);
}

__device__ inline float bf2f(unsigned short h, unsigned short l)
{
  return __uint_as_float((unsigned)h << 16) + __uint_as_float((unsigned)l << 16);
}

// bijective XCD chunking (m204): consecutive logical ids land on one XCD
__device__ inline int xcd_swz(int bid, int nwg)
{
  int xcd = bid & 7, pos = bid >> 3;
  int q = nwg >> 3, r = nwg & 7;
  return (xcd < r ? xcd * (q + 1) : r * (q + 1) + (xcd - r) * q) + pos;
}

// ---------- weight transpose+split: w[co][ci][r9] f32 -> [co][r9][ci] bf16 hi/lo
__global__ __launch_bounds__(256) void wsplit_k(
    const float* __restrict__ w, unsigned short* __restrict__ oh,
    unsigned short* __restrict__ ol, int CO, int CI)
{
  int idx = blockIdx.x * 256 + threadIdx.x;          // grid sized exactly
  int ci = idx % CI;
  int t2 = idx / CI;
  int r = t2 % 9, co = t2 / 9;
  float f = w[((size_t)co * CI + ci) * 9 + r];
  unsigned short h, l;
  split1(f, h, l);
  oh[idx] = h; ol[idx] = l;
}

// ---------- conv1: 3->96 k3 s1 p1 + relu -> NHWC bf16 hi/lo ----------
__global__ __launch_bounds__(256) void conv1_k(
    const float* __restrict__ x, const float* __restrict__ wt,
    const float* __restrict__ bias, unsigned short* __restrict__ oh,
    unsigned short* __restrict__ ol)
{
  int idx = blockIdx.x * 256 + threadIdx.x;     // (b, h, w)
  int w = idx & 31, h = (idx >> 5) & 31, b = idx >> 10;
  int co0 = blockIdx.y * 24;                    // co-slice

  float xv[27];
  const float* xb = x + (size_t)b * 3072;
  #pragma unroll
  for (int ci = 0; ci < 3; ++ci)
    #pragma unroll
    for (int dh = 0; dh < 3; ++dh) {
      int ih = h + dh - 1;
      #pragma unroll
      for (int dw = 0; dw < 3; ++dw) {
        int iw = w + dw - 1;
        bool ok = ((unsigned)ih < 32u) & ((unsigned)iw < 32u);
        xv[ci * 9 + dh * 3 + dw] = ok ? xb[(ci << 10) + (ih << 5) + iw] : 0.f;
      }
    }

  size_t obase = ((size_t)b * 1024 + (h << 5) + w) * 96 + co0;
  const float* wp = wt + (size_t)co0 * 27;      // wave-uniform -> s_load
  #pragma unroll 2
  for (int cp = 0; cp < 12; ++cp) {
    float a0 = bias[co0 + 2 * cp], a1 = bias[co0 + 2 * cp + 1];
    #pragma unroll
    for (int k = 0; k < 27; ++k) {
      a0 += xv[k] * wp[(2 * cp) * 27 + k];
      a1 += xv[k] * wp[(2 * cp + 1) * 27 + k];
    }
    a0 = fmaxf(a0, 0.f); a1 = fmaxf(a1, 0.f);
    unsigned short h0, l0, h1, l1;
    split1(a0, h0, l0); split1(a1, h1, l1);
    *(unsigned*)(oh + obase + 2 * cp) = (unsigned)h0 | ((unsigned)h1 << 16);
    *(unsigned*)(ol + obase + 2 * cp) = (unsigned)l0 | ((unsigned)l1 << 16);
  }
}

// ---------- maxpool k3 s2 p1 on NHWC bf16 hi/lo pairs ----------
template <int C, int H>
__global__ __launch_bounds__(256) void maxpool_bf(
    const unsigned short* __restrict__ inh, const unsigned short* __restrict__ inl,
    unsigned short* __restrict__ outh, unsigned short* __restrict__ outl)
{
  constexpr int Ho = H >> 1;
  int idx = blockIdx.x * 256 + threadIdx.x;
  int c = idx % C;
  int q = idx / C;
  int wo = q % Ho;
  int q2 = q / Ho;
  int ho = q2 % Ho, b = q2 / Ho;
  float best = -3.4e38f;
  unsigned short bh = 0, bl = 0;
  #pragma unroll
  for (int dh = 0; dh < 3; ++dh) {
    int ih = 2 * ho - 1 + dh;
    if ((unsigned)ih >= (unsigned)H) continue;
    #pragma unroll
    for (int dw = 0; dw < 3; ++dw) {
      int iw = 2 * wo - 1 + dw;
      if ((unsigned)iw >= (unsigned)H) continue;
      size_t off = ((size_t)(b * H + ih) * H + iw) * C + c;
      unsigned short uh = inh[off], ul = inl[off];
      float f = bf2f(uh, ul);
      if (f > best) { best = f; bh = uh; bl = ul; }
    }
  }
  outh[idx] = bh; outl[idx] = bl;
}

// ---------- bias + relu + bf16 split, NHWC fp32 -> hi/lo planes ----------
__global__ __launch_bounds__(256) void bias_split_k(
    const float* __restrict__ in, const float* __restrict__ bias,
    unsigned short* __restrict__ oh, unsigned short* __restrict__ ol,
    int C, int total2)
{
  int idx = blockIdx.x * 256 + threadIdx.x;
  if (idx >= total2) return;
  int e0 = idx * 2;
  int c = e0 % C;
  float f0 = fmaxf(in[e0] + bias[c], 0.f);
  float f1 = fmaxf(in[e0 + 1] + bias[c + 1], 0.f);
  unsigned short h0, l0, h1, l1;
  split1(f0, h0, l0); split1(f1, h1, l1);
  *(unsigned*)(oh + e0) = (unsigned)h0 | ((unsigned)h1 << 16);
  *(unsigned*)(ol + e0) = (unsigned)l0 | ((unsigned)l1 << 16);
}

// ---------- conv as 128x128-tile MFMA GEMM, NHWC bf16 hi/lo ----------
// A = pixels (M), B = weights (N = CO). K order (dh,dw,ci), CI%32==0 so each
// 32-k step sits in one (dh,dw). Staging: thread t loads row t>>2, kchunk t&3
// (contiguous 64B rows). LDS [rg][row][kc], kc XOR row&3.
template <int CI, int H, int PAD, int WO, int CO, int MT, bool SPLIT>
__global__ __launch_bounds__(256) void conv128(
    const unsigned short* __restrict__ inh, const unsigned short* __restrict__ inl,
    const unsigned short* __restrict__ wh, const unsigned short* __restrict__ wl,
    const float* __restrict__ bias, unsigned short* __restrict__ outh,
    unsigned short* __restrict__ outl, float* __restrict__ outf,
    int relu, int KC)
{
  constexpr int K = CI * 9;
  constexpr int NPIX = WO * WO;
  __shared__ uint4 Ah[512], Al[512], Bh[512], Bl[512];   // 32KB

  int id = xcd_swz(blockIdx.x, gridDim.x);
  int ntile = id / MT, mtile = id - ntile * MT;
  int n0 = ntile * 128, m0 = mtile * 128;
  int kbeg = SPLIT ? blockIdx.z * KC : 0;
  int kend = SPLIT ? kbeg + KC : K;

  int t = threadIdx.x;
  int lane = t & 63;
  int wave = __builtin_amdgcn_readfirstlane(t >> 6);
  int wm = wave & 1, wn = wave >> 1;
  int lr = lane & 15, lq = lane >> 4;

  // staging roles
  int srow = (t >> 2) & 63;                  // row within 64-group
  int kc8 = (t & 3) * 8;                     // k offset within 32-chunk
  int sidx = srow * 4 + ((t & 3) ^ (srow & 3));

  // A-side pixel geometry for both row-groups
  int ih0g[2], iw0g[2];
  size_t ibaseg[2];
  #pragma unroll
  for (int g = 0; g < 2; ++g) {
    int pix = m0 + g * 64 + srow;
    int bpix = pix / NPIX, xy = pix - bpix * NPIX;
    int ho = xy / WO, wo = xy - ho * WO;
    ih0g[g] = ho - PAD; iw0g[g] = wo - PAD;
    ibaseg[g] = (size_t)bpix * H * H;
  }

  uint4 pah[2], pal_[2], pbh[2], pbl[2];
  auto loadA = [&](int k0) {
    int r = k0 / CI;
    int cib = k0 - r * CI + kc8;
    int dh = r / 3, dw = r - dh * 3;
    #pragma unroll
    for (int g = 0; g < 2; ++g) {
      int ih = ih0g[g] + dh, iw = iw0g[g] + dw;
      bool ok = ((unsigned)ih < (unsigned)H) & ((unsigned)iw < (unsigned)H);
      if (ok) {
        size_t ad = (ibaseg[g] + (size_t)ih * H + iw) * CI + cib;
        pah[g] = *(const uint4*)(inh + ad);
        pal_[g] = *(const uint4*)(inl + ad);
      } else {
        pah[g] = make_uint4(0u, 0u, 0u, 0u);
        pal_[g] = make_uint4(0u, 0u, 0u, 0u);
      }
    }
  };
  auto loadB = [&](int k0) {
    #pragma unroll
    for (int g = 0; g < 2; ++g) {
      size_t ad = (size_t)(n0 + g * 64 + srow) * K + k0 + kc8;
      pbh[g] = *(const uint4*)(wh + ad);
      pbl[g] = *(const uint4*)(wl + ad);
    }
  };

  loadA(kbeg); loadB(kbeg);
  f4_t acc[4][4];
  #pragma unroll
  for (int mt = 0; mt < 4; ++mt)
    #pragma unroll
    for (int nt = 0; nt < 4; ++nt) acc[mt][nt] = (f4_t)0.0f;

  for (int k0 = kbeg; k0 < kend; k0 += 32) {
    if (k0 > kbeg) __syncthreads();
    Ah[sidx] = pah[0]; Ah[256 + sidx] = pah[1];
    Al[sidx] = pal_[0]; Al[256 + sidx] = pal_[1];
    Bh[sidx] = pbh[0]; Bh[256 + sidx] = pbh[1];
    Bl[sidx] = pbl[0]; Bl[256 + sidx] = pbl[1];
    __syncthreads();
    if (k0 + 32 < kend) { loadA(k0 + 32); loadB(k0 + 32); }

    int xk = lq ^ (lr & 3);
    int aBase = wm * 256 + lr * 4 + xk;
    int bBase = wn * 256 + lr * 4 + xk;
    bf8_t bvh[4], bvl[4];
    #pragma unroll
    for (int nt = 0; nt < 4; ++nt) {
      bvh[nt] = *(const bf8_t*)&Bh[bBase + nt * 64];
      bvl[nt] = *(const bf8_t*)&Bl[bBase + nt * 64];
    }
    #pragma unroll
    for (int mt = 0; mt < 4; ++mt) {
      bf8_t avh = *(const bf8_t*)&Ah[aBase + mt * 64];
      bf8_t avl = *(const bf8_t*)&Al[aBase + mt * 64];
      #pragma unroll
      for (int nt = 0; nt < 4; ++nt) {
        acc[mt][nt] = __builtin_amdgcn_mfma_f32_16x16x32_bf16(avh, bvh[nt], acc[mt][nt], 0, 0, 0);
        acc[mt][nt] = __builtin_amdgcn_mfma_f32_16x16x32_bf16(avh, bvl[nt], acc[mt][nt], 0, 0, 0);
        acc[mt][nt] = __builtin_amdgcn_mfma_f32_16x16x32_bf16(avl, bvh[nt], acc[mt][nt], 0, 0, 0);
      }
    }
  }

  // D: row = pixel m, col = co n; NHWC flat m*CO + n
  #pragma unroll
  for (int mt = 0; mt < 4; ++mt)
    #pragma unroll
    for (int nt = 0; nt < 4; ++nt) {
      #pragma unroll
      for (int r = 0; r < 4; ++r) {
        int m = m0 + wm * 64 + mt * 16 + lq * 4 + r;
        int n = n0 + wn * 64 + nt * 16 + lr;
        size_t oidx = (size_t)m * CO + n;
        if (SPLIT) {
          atomicAdd(outf + oidx, acc[mt][nt][r]);
        } else {
          float vv = acc[mt][nt][r] + bias[n];
          if (relu) vv = fmaxf(vv, 0.f);
          unsigned short h, l;
          split1(vv, h, l);
          outh[oidx] = h; outl[oidx] = l;
        }
      }
    }
}

// ---------- FC as bf16x2-split MFMA GEMM, split-K, atomic partials ----------
__global__ __launch_bounds__(256) void fc_mfma(
    const float* __restrict__ A, const float* __restrict__ W,
    float* __restrict__ C, int K, int N, int KC)
{
  __shared__ uint4 Ah[256], Al[256], Bh[256], Bl[256];
  int n0 = blockIdx.x * 64, m0 = blockIdx.y * 64;
  int kbeg = blockIdx.z * KC, kend = kbeg + KC;
  int t = threadIdx.x;
  int lane = t & 63;
  int wave = __builtin_amdgcn_readfirstlane(t >> 6);
  int wm = wave & 1, wn = wave >> 1;
  int lr = lane & 15, lq = lane >> 4;
  int smA = t >> 2, sgA = t & 3;

  float fa[8], fb[8];
  auto loadA = [&](int k0) {
    const float4* ap = (const float4*)(A + (size_t)(m0 + smA) * K + k0 + sgA * 8);
    float4 a0 = ap[0], a1 = ap[1];
    fa[0] = a0.x; fa[1] = a0.y; fa[2] = a0.z; fa[3] = a0.w;
    fa[4] = a1.x; fa[5] = a1.y; fa[6] = a1.z; fa[7] = a1.w;
  };
  auto loadB = [&](int k0) {
    const float* wp = W + (size_t)(k0 + wave * 8) * N + n0 + lane;
    #pragma unroll
    for (int j = 0; j < 8; ++j) fb[j] = wp[(size_t)j * N];
  };

  loadA(kbeg); loadB(kbeg);
  f4_t acc[2][2];
  #pragma unroll
  for (int mt = 0; mt < 2; ++mt)
    #pragma unroll
    for (int nt = 0; nt < 2; ++nt) acc[mt][nt] = (f4_t)0.0f;

  for (int k0 = kbeg; k0 < kend; k0 += 32) {
    if (k0 > kbeg) __syncthreads();
    unsigned ha[4], la[4], hb[4], lb[4];
    cvt_hilo8(fa, ha, la);
    cvt_hilo8(fb, hb, lb);
    Ah[sgA * 64 + smA] = make_uint4(ha[0], ha[1], ha[2], ha[3]);
    Al[sgA * 64 + smA] = make_uint4(la[0], la[1], la[2], la[3]);
    Bh[wave * 64 + lane] = make_uint4(hb[0], hb[1], hb[2], hb[3]);
    Bl[wave * 64 + lane] = make_uint4(lb[0], lb[1], lb[2], lb[3]);
    __syncthreads();
    if (k0 + 32 < kend) { loadA(k0 + 32); loadB(k0 + 32); }
    bf8_t av_h[2], av_l[2], bv_h[2], bv_l[2];
    #pragma unroll
    for (int mt = 0; mt < 2; ++mt) {
      int ui = lq * 64 + wm * 32 + mt * 16 + lr;
      av_h[mt] = *(const bf8_t*)&Ah[ui];
      av_l[mt] = *(const bf8_t*)&Al[ui];
    }
    #pragma unroll
    for (int nt = 0; nt < 2; ++nt) {
      int ui = lq * 64 + wn * 32 + nt * 16 + lr;
      bv_h[nt] = *(const bf8_t*)&Bh[ui];
      bv_l[nt] = *(const bf8_t*)&Bl[ui];
    }
    #pragma unroll
    for (int mt = 0; mt < 2; ++mt)
      #pragma unroll
      for (int nt = 0; nt < 2; ++nt) {
        acc[mt][nt] = __builtin_amdgcn_mfma_f32_16x16x32_bf16(av_h[mt], bv_h[nt], acc[mt][nt], 0, 0, 0);
        acc[mt][nt] = __builtin_amdgcn_mfma_f32_16x16x32_bf16(av_h[mt], bv_l[nt], acc[mt][nt], 0, 0, 0);
        acc[mt][nt] = __builtin_amdgcn_mfma_f32_16x16x32_bf16(av_l[mt], bv_h[nt], acc[mt][nt], 0, 0, 0);
      }
  }
  #pragma unroll
  for (int mt = 0; mt < 2; ++mt)
    #pragma unroll
    for (int nt = 0; nt < 2; ++nt) {
      #pragma unroll
      for (int r = 0; r < 4; ++r) {
        int m = m0 + wm * 32 + mt * 16 + lq * 4 + r;
        int n = n0 + wn * 32 + nt * 16 + lr;
        atomicAdd(C + (size_t)m * N + n, acc[mt][nt][r]);
      }
    }
}

// ---------- squash8 + pcaps bias; p[b,pix36,co256] NHWC -> u_t[i,e,b] ----------
__global__ __launch_bounds__(256) void squash8_k(
    const float* __restrict__ p, const float* __restrict__ pb,
    float* __restrict__ ut)
{
  int idx = blockIdx.x * 256 + threadIdx.x;
  if (idx >= 147456) return;
  int b = idx & 127, i = idx >> 7;
  float pv[8];
  #pragma unroll
  for (int e = 0; e < 8; ++e) {
    int f = i * 8 + e;
    int co = f / 36, pix = f - co * 36;
    pv[e] = p[((size_t)b * 36 + pix) * 256 + co] + pb[co];
  }
  float n2 = 0.f;
  #pragma unroll
  for (int e = 0; e < 8; ++e) n2 += pv[e] * pv[e];
  float sc = (n2 / (1.f + n2)) * rsqrtf(n2 + 1e-8f);
  #pragma unroll
  for (int e = 0; e < 8; ++e)
    ut[(size_t)i * 1024 + e * 128 + b] = pv[e] * sc;
}

// ---------- squash16: s[b,o,16] -> v[b,o,16] + v_t[o,d,b] ----------
__global__ __launch_bounds__(256) void caps_squash16(
    const float* __restrict__ s, float* __restrict__ v, float* __restrict__ vt)
{
  int idx = blockIdx.x * 256 + threadIdx.x;
  if (idx >= 12800) return;
  int b = idx / 100, o = idx % 100;
  const float4* sp = (const float4*)(s + (size_t)idx * 16);
  float4 a = sp[0], bb = sp[1], c = sp[2], d = sp[3];
  float n2 = a.x * a.x + a.y * a.y + a.z * a.z + a.w * a.w +
             bb.x * bb.x + bb.y * bb.y + bb.z * bb.z + bb.w * bb.w +
             c.x * c.x + c.y * c.y + c.z * c.z + c.w * c.w +
             d.x * d.x + d.y * d.y + d.z * d.z + d.w * d.w;
  float sc = (n2 / (1.f + n2)) * rsqrtf(n2 + 1e-8f);
  float vv[16] = {a.x, a.y, a.z, a.w, bb.x, bb.y, bb.z, bb.w,
                  c.x, c.y, c.z, c.w, d.x, d.y, d.z, d.w};
  float4* vp = (float4*)(v + (size_t)idx * 16);
  float4 o0 = {vv[0] * sc, vv[1] * sc, vv[2] * sc, vv[3] * sc};
  float4 o1 = {vv[4] * sc, vv[5] * sc, vv[6] * sc, vv[7] * sc};
  float4 o2 = {vv[8] * sc, vv[9] * sc, vv[10] * sc, vv[11] * sc};
  float4 o3 = {vv[12] * sc, vv[13] * sc, vv[14] * sc, vv[15] * sc};
  vp[0] = o0; vp[1] = o1; vp[2] = o2; vp[3] = o3;
  #pragma unroll
  for (int dd = 0; dd < 16; ++dd)
    vt[((size_t)o * 16 + dd) * 128 + b] = vv[dd] * sc;
}

// ---------- routing s-pass as per-o MFMA GEMM ----------
__global__ __launch_bounds__(256) void caps_spass_mfma(
    const float* __restrict__ W, const float* __restrict__ ut,
    const float* __restrict__ ct, float* __restrict__ s, int uniform)
{
  __shared__ uint4 Ah[512], Al[512];               // [quad(4)][b(128)] 8KB each
  int o = blockIdx.x, ks = blockIdx.y;
  int t = threadIdx.x;
  int lane = t & 63;
  int wave = __builtin_amdgcn_readfirstlane(t >> 6);
  int lr = lane & 15, lq = lane >> 4;
  int b = t & 127, half = t >> 7;                  // staging role
  int i0 = ks * 144;

  float fu[16], fc[2], fw[8];
  auto loadUC = [&](int j) {
    int ib = i0 + j * 4 + half * 2;
    #pragma unroll
    for (int q = 0; q < 2; ++q) {
      int i = ib + q;
      #pragma unroll
      for (int e = 0; e < 8; ++e)
        fu[q * 8 + e] = ut[(size_t)i * 1024 + e * 128 + b];   // coalesced
      fc[q] = uniform ? 0.01f : ct[((size_t)o * 1152 + i) * 128 + b];
    }
  };
  auto loadW = [&](int j) {
    int i = i0 + j * 4 + lq;
    const float4* wp = (const float4*)(W + (((size_t)o * 1152 + i) * 16 + lr) * 8);
    float4 w0 = wp[0], w1 = wp[1];
    fw[0] = w0.x; fw[1] = w0.y; fw[2] = w0.z; fw[3] = w0.w;
    fw[4] = w1.x; fw[5] = w1.y; fw[6] = w1.z; fw[7] = w1.w;
  };

  loadUC(0); loadW(0);
  f4_t acc[2];
  acc[0] = (f4_t)0.0f; acc[1] = (f4_t)0.0f;

  for (int j = 0; j < 36; ++j) {
    float cu[16];
    #pragma unroll
    for (int q = 0; q < 2; ++q)
      #pragma unroll
      for (int e = 0; e < 8; ++e)
        cu[q * 8 + e] = fc[q] * fu[q * 8 + e];
    unsigned h0[4], l0[4], h1[4], l1[4], wh[4], wl[4];
    cvt_hilo8(cu, h0, l0);
    cvt_hilo8(cu + 8, h1, l1);
    cvt_hilo8(fw, wh, wl);                          // current W split (before prefetch)
    uint4 uwh = make_uint4(wh[0], wh[1], wh[2], wh[3]);
    uint4 uwl = make_uint4(wl[0], wl[1], wl[2], wl[3]);
    bf8_t bfh = *(const bf8_t*)&uwh;
    bf8_t bfl = *(const bf8_t*)&uwl;
    if (j > 0) __syncthreads();
    Ah[(half * 2 + 0) * 128 + b] = make_uint4(h0[0], h0[1], h0[2], h0[3]);
    Al[(half * 2 + 0) * 128 + b] = make_uint4(l0[0], l0[1], l0[2], l0[3]);
    Ah[(half * 2 + 1) * 128 + b] = make_uint4(h1[0], h1[1], h1[2], h1[3]);
    Al[(half * 2 + 1) * 128 + b] = make_uint4(l1[0], l1[1], l1[2], l1[3]);
    __syncthreads();
    if (j + 1 < 36) { loadUC(j + 1); loadW(j + 1); }
    #pragma unroll
    for (int mt = 0; mt < 2; ++mt) {
      int bidx = wave * 16 + mt * 64 + lr;
      bf8_t avh = *(const bf8_t*)&Ah[lq * 128 + bidx];
      bf8_t avl = *(const bf8_t*)&Al[lq * 128 + bidx];
      acc[mt] = __builtin_amdgcn_mfma_f32_16x16x32_bf16(avh, bfh, acc[mt], 0, 0, 0);
      acc[mt] = __builtin_amdgcn_mfma_f32_16x16x32_bf16(avh, bfl, acc[mt], 0, 0, 0);
      acc[mt] = __builtin_amdgcn_mfma_f32_16x16x32_bf16(avl, bfh, acc[mt], 0, 0, 0);
    }
  }
  // D layout: col(d)=lane&15, row(b)=lq*4+r
  #pragma unroll
  for (int mt = 0; mt < 2; ++mt)
    #pragma unroll
    for (int r = 0; r < 4; ++r) {
      int bb = wave * 16 + mt * 64 + lq * 4 + r;
      atomicAdd(s + ((size_t)bb * 100 + o) * 16 + lr, acc[mt][r]);
    }
}

// ---------- routing b-update as MFMA ----------
__global__ __launch_bounds__(256) void caps_bupdate(
    const float* __restrict__ W, const float* __restrict__ ut,
    const float* __restrict__ vt, float* __restrict__ blogt, int accum)
{
  __shared__ __align__(16) float Wt[64 * 160];   // [li][e(stride 20)][d] 40KB
  int o = blockIdx.x, ic = blockIdx.y;
  int t = threadIdx.x;
  int lane = t & 63;
  int wave = __builtin_amdgcn_readfirstlane(t >> 6);
  int lr = lane & 15, lq = lane >> 4;
  int dhalf = (lq & 1) << 3;        // which 8 d's this lq-quarter covers
  int hl = lq >> 1;                 // 0: hi plane (k<16), 1: lo plane (k>=16)

  {
    const float4* Wg = (const float4*)(W + ((size_t)o * 1152 + (size_t)ic * 64) * 128);
    for (int l = t; l < 2048; l += 256) {
      float4 w = Wg[l];
      int li = l >> 5;
      int rem = l & 31;
      int d = rem >> 1;
      int e0 = (rem & 1) << 2;
      float* dst = &Wt[li * 160 + e0 * 20 + d];
      dst[0] = w.x; dst[20] = w.y; dst[40] = w.z; dst[60] = w.w;
    }
  }

  bf8_t B1[8], B2[8];
  #pragma unroll
  for (int nt = 0; nt < 8; ++nt) {
    int b = nt * 16 + lr;
    float vv[8];
    #pragma unroll
    for (int j = 0; j < 8; ++j)
      vv[j] = vt[((size_t)o * 16 + dhalf + j) * 128 + b];
    unsigned h[4], l2[4];
    cvt_hilo8(vv, h, l2);
    uint4 uh = make_uint4(h[0], h[1], h[2], h[3]);
    uint4 ul = (lq < 2) ? make_uint4(l2[0], l2[1], l2[2], l2[3])
                        : make_uint4(0u, 0u, 0u, 0u);
    B1[nt] = *(const bf8_t*)&uh;
    B2[nt] = *(const bf8_t*)&ul;
  }
  __syncthreads();

  unsigned lomask = hl ? 0xFFFF0000u : 0u;

  for (int mi = 0; mi < 8; ++mi) {
    int mt = wave * 8 + mi;
    int liA = mt * 2 + (lr >> 3);
    int eA = lr & 7;
    const float* wp = &Wt[liA * 160 + eA * 20 + dhalf];
    float4 wa = *(const float4*)wp;
    float4 wb = *(const float4*)(wp + 4);
    float fw[8] = {wa.x, wa.y, wa.z, wa.w, wb.x, wb.y, wb.z, wb.w};
    unsigned ha[4];
    #pragma unroll
    for (int j = 0; j < 4; ++j) {
      float f0 = fw[2 * j], f1 = fw[2 * j + 1];
      f0 -= __uint_as_float(__float_as_uint(f0) & lomask);
      f1 -= __uint_as_float(__float_as_uint(f1) & lomask);
      ha[j] = (__float_as_uint(f0) >> 16) | (__float_as_uint(f1) & 0xFFFF0000u);
    }
    uint4 ua = make_uint4(ha[0], ha[1], ha[2], ha[3]);
    bf8_t A = *(const bf8_t*)&ua;

    int gi = ic * 64 + mt * 2 + hl;
    const float* up = ut + (size_t)gi * 1024 + (size_t)(((lq & 1) << 2)) * 128;
    #pragma unroll
    for (int nt = 0; nt < 8; ++nt) {
      f4_t acc = (f4_t)0.0f;
      acc = __builtin_amdgcn_mfma_f32_16x16x32_bf16(A, B1[nt], acc, 0, 0, 0);
      acc = __builtin_amdgcn_mfma_f32_16x16x32_bf16(A, B2[nt], acc, 0, 0, 0);
      int b = nt * 16 + lr;
      float p = acc[0] * up[b] + acc[1] * up[128 + b] +
                acc[2] * up[256 + b] + acc[3] * up[384 + b];
      p += __shfl_xor(p, 16);
      if (!(lq & 1)) {
        size_t off = ((size_t)o * 1152 + gi) * 128 + b;
        if (accum) blogt[off] += p; else blogt[off] = p;
      }
    }
  }
}

// ---------- softmax over o per (i,b), transposed layouts ----------
__global__ __launch_bounds__(256) void caps_softmax(
    const float* __restrict__ blogt, float* __restrict__ ct)
{
  int idx = blockIdx.x * 256 + threadIdx.x;
  if (idx >= 147456) return;
  const float* bp = blogt + idx;
  float m = -3.4e38f;
  for (int o = 0; o < 100; ++o) m = fmaxf(m, bp[(size_t)o * 147456]);
  float sum = 0.f;
  for (int o = 0; o < 100; ++o) sum += __expf(bp[(size_t)o * 147456] - m);
  float inv = 1.f / sum;
  for (int o = 0; o < 100; ++o)
    ct[(size_t)o * 147456 + idx] = __expf(bp[(size_t)o * 147456] - m) * inv;
}

// ---------- bias + optional relu, in place ----------
__global__ __launch_bounds__(256) void bias_act_k(
    float* __restrict__ C, const float* __restrict__ bias, int N, int total, int relu)
{
  int idx = blockIdx.x * 256 + threadIdx.x;
  if (idx >= total) return;
  float vv = C[idx] + bias[idx % N];
  if (relu) vv = fmaxf(vv, 0.f);
  C[idx] = vv;
}

// ---------- fc3 ----------
__global__ __launch_bounds__(128) void fc3_seed(
    const float* __restrict__ bias, float* __restrict__ out)
{
  int idx = blockIdx.x * 128 + threadIdx.x;
  if (idx < 12800) out[idx] = bias[idx % 100];
}

__global__ __launch_bounds__(128) void fc3_sk(
    const float* __restrict__ A, const float* __restrict__ W,
    float* __restrict__ out)
{
  __shared__ float Al[1024];
  int m = blockIdx.x, z = blockIdx.y, t = threadIdx.x;
  int kbeg = z * 1024;
  const float* ap = A + (size_t)m * 4096 + kbeg;
  for (int l = t; l < 1024; l += 128) Al[l] = ap[l];
  __syncthreads();
  if (t < 100) {
    float acc = 0.f;
    const float* wp = W + (size_t)kbeg * 100 + t;
    #pragma unroll 8
    for (int k = 0; k < 1024; ++k) acc += Al[k] * wp[(size_t)k * 100];
    atomicAdd(out + m * 100 + t, acc);
  }
}

// ============================================================================
extern "C" void kernel_launch(void* const* d_in, const int* in_sizes, int n_in,
                              void* d_out, int out_size, void* d_ws, size_t ws_size,
                              hipStream_t stream)
{
  (void)in_sizes; (void)n_in; (void)out_size; (void)ws_size;
  const float* x   = (const float*)d_in[0];
  const float* cw1 = (const float*)d_in[1];
  const float* cb1 = (const float*)d_in[2];
  const float* cw2 = (const float*)d_in[3];
  const float* cb2 = (const float*)d_in[4];
  const float* cw3 = (const float*)d_in[5];
  const float* cb3 = (const float*)d_in[6];
  const float* pw  = (const float*)d_in[7];
  const float* pb  = (const float*)d_in[8];
  const float* Wc  = (const float*)d_in[9];
  const float* fw1 = (const float*)d_in[10];
  const float* fb1 = (const float*)d_in[11];
  const float* fw2 = (const float*)d_in[12];
  const float* fb2 = (const float*)d_in[13];
  const float* fw3 = (const float*)d_in[14];
  const float* fb3 = (const float*)d_in[15];
  float* ws = (float*)d_ws;

  const size_t OFF_A  = 0;          // act planes; later blog_t [o,i,b]
  const size_t OFF_B  = 12582912;   // pooled planes
  const size_t OFF_U  = 15728640;   // u_t [1152,8,128]
  const size_t OFF_P  = 16908288;   // p [128,36,256] NHWC; later v_t [100,16,128]
  const size_t OFF_C  = 18087936;   // weight planes + h3f (backbone) / c_t (routing)
  const size_t OFF_V  = 32833536;   // v [128,100,16]
  const size_t OFF_S  = 33038336;   // s [128,100,16]
  const size_t OFF_F1 = 33243136;   // f1 [128,4096]
  const size_t OFF_F2 = 33767424;   // f2 [128,4096]

  float* ut    = ws + OFF_U;
  float* p     = ws + OFF_P;
  float* vt    = ws + OFF_P;        // reuses p region after squash8
  float* ct    = ws + OFF_C;
  float* v     = ws + OFF_V;
  float* s     = ws + OFF_S;
  float* f1    = ws + OFF_F1;
  float* f2    = ws + OFF_F2;
  float* blogt = ws + OFF_A;

  // bf16 activation planes (ushort views)
  unsigned short* h1h  = (unsigned short*)(ws + OFF_A);   // [128,32,32,96]
  unsigned short* h1l  = h1h + 12582912;
  unsigned short* mp1h = (unsigned short*)(ws + OFF_B);   // [128,16,16,96]
  unsigned short* mp1l = mp1h + 3145728;
  unsigned short* h2h  = (unsigned short*)(ws + OFF_A);   // [128,16,16,256]
  unsigned short* h2l  = h2h + 8388608;
  unsigned short* mp2h = (unsigned short*)(ws + OFF_B);   // [128,8,8,256]
  unsigned short* mp2l = mp2h + 2097152;
  unsigned short* h3h  = (unsigned short*)(ws + OFF_A);   // [128,8,8,384]
  unsigned short* h3l  = h3h + 3145728;

  // weight planes + conv3 f32 accum at OFF_C (dead before routing's ct)
  unsigned short* wc2h = (unsigned short*)(ws + OFF_C);   // [256][9][96]
  unsigned short* wc2l = wc2h + 221184;
  unsigned short* wc3h = wc2l + 221184;                   // [384][9][256]
  unsigned short* wc3l = wc3h + 884736;
  unsigned short* pwth = wc3l + 884736;                   // [256][9][384]
  unsigned short* pwtl = pwth + 884736;
  float* h3f = ws + OFF_C + 2097152;                      // [128,8,8,384] f32

  hipMemsetAsync(p,   0, (size_t)1179648 * 4, stream);
  hipMemsetAsync(h3f, 0, (size_t)3145728 * 4, stream);
  hipMemsetAsync(f1,  0, (size_t)524288 * 4, stream);
  hipMemsetAsync(f2,  0, (size_t)524288 * 4, stream);

  // Weight transpose + bf16 split (tiny)
  wsplit_k<<<864, 256, 0, stream>>>(cw2, wc2h, wc2l, 256, 96);
  wsplit_k<<<3456, 256, 0, stream>>>(cw3, wc3h, wc3l, 384, 256);
  wsplit_k<<<3456, 256, 0, stream>>>(pw,  pwth, pwtl, 256, 384);

  // Backbone (NHWC bf16 hi/lo planes)
  conv1_k<<<dim3(512, 4), 256, 0, stream>>>(x, cw1, cb1, h1h, h1l);
  maxpool_bf<96, 32><<<12288, 256, 0, stream>>>(h1h, h1l, mp1h, mp1l);
  conv128<96, 16, 1, 16, 256, 256, false><<<512, 256, 0, stream>>>(
      mp1h, mp1l, wc2h, wc2l, cb2, h2h, h2l, nullptr, 1, 0);
  maxpool_bf<256, 16><<<8192, 256, 0, stream>>>(h2h, h2l, mp2h, mp2l);
  // conv3 split-K z=4 (768 blocks), fp32 atomic accum -> bias/relu/split
  conv128<256, 8, 1, 8, 384, 64, true><<<dim3(192, 1, 4), 256, 0, stream>>>(
      mp2h, mp2l, wc3h, wc3l, cb3, nullptr, nullptr, h3f, 0, 576);
  bias_split_k<<<6144, 256, 0, stream>>>(h3f, cb3, h3h, h3l, 384, 1572864);
  // pcaps split-K z=6 (432 blocks)
  conv128<384, 8, 0, 6, 256, 36, true><<<dim3(72, 1, 6), 256, 0, stream>>>(
      h3h, h3l, pwth, pwtl, pb, nullptr, nullptr, p, 0, 576);
  squash8_k<<<576, 256, 0, stream>>>(p, pb, ut);          // u_t [1152,8,128]

  // Dynamic routing (3 iterations)
  for (int r = 0; r < 3; ++r) {
    hipMemsetAsync(s, 0, (size_t)204800 * 4, stream);
    if (r == 0) {
      caps_spass_mfma<<<dim3(100, 8), 256, 0, stream>>>(Wc, ut, ut /*dummy*/, s, 1);
    } else {
      caps_softmax<<<576, 256, 0, stream>>>(blogt, ct);
      caps_spass_mfma<<<dim3(100, 8), 256, 0, stream>>>(Wc, ut, ct, s, 0);
    }
    caps_squash16<<<50, 256, 0, stream>>>(s, v, vt);
    if (r < 2)
      caps_bupdate<<<dim3(100, 18), 256, 0, stream>>>(Wc, ut, vt, blogt, r);
  }

  // FC head; v is already [128,1600] flat
  fc_mfma<<<dim3(64, 2, 2), 256, 0, stream>>>(v,  fw1, f1, 1600, 4096, 800);
  bias_act_k<<<2048, 256, 0, stream>>>(f1, fb1, 4096, 524288, 1);
  fc_mfma<<<dim3(64, 2, 4), 256, 0, stream>>>(f1, fw2, f2, 4096, 4096, 1024);
  bias_act_k<<<2048, 256, 0, stream>>>(f2, fb2, 4096, 524288, 1);
  fc3_seed<<<100, 128, 0, stream>>>(fb3, (float*)d_out);
  fc3_sk<<<dim3(128, 4), 128, 0, stream>>>(f2, fw3, (float*)d_out);
}